// Round 8
// baseline (372.619 us; speedup 1.0000x reference)
//
#include <hip/hip_runtime.h>

typedef unsigned short u16;
typedef __bf16 bf16x8 __attribute__((ext_vector_type(8)));
typedef float f32x4 __attribute__((ext_vector_type(4)));
typedef u16 u16x8 __attribute__((ext_vector_type(8)));
typedef u16 u16x4 __attribute__((ext_vector_type(4)));

static __device__ __forceinline__ u16 f2bf(float x){
  unsigned u = __float_as_uint(x);
  u += 0x7fffu + ((u >> 16) & 1u);
  return (u16)(u >> 16);
}
static __device__ __forceinline__ float bf2f(u16 u){
  return __uint_as_float(((unsigned)u) << 16);
}

#define MFMA __builtin_amdgcn_mfma_f32_16x16x32_bf16

#define GLD1(GP, LP) __builtin_amdgcn_global_load_lds( \
    (const __attribute__((address_space(1))) unsigned int*)(GP), \
    (__attribute__((address_space(3))) unsigned int*)(LP), 16, 0, 0)

// ---- 16-acc core macros (named SSA vars only; arrays get memory-lowered) ----
#define DECL_ACC \
  f32x4 acc00={},acc01={},acc02={},acc03={}, \
        acc10={},acc11={},acc12={},acc13={}, \
        acc20={},acc21={},acc22={},acc23={}, \
        acc30={},acc31={},acc32={},acc33={};

#define CORE_SETUP \
  int tid = threadIdx.x; \
  int lane = tid & 63, w = tid >> 6; \
  int wm = (w >> 1) * 64, wn = (w & 1) * 64; \
  int quad = lane >> 4, l16 = lane & 15; \
  int r8 = lane >> 3, c8 = lane & 7; \
  int p0 = quad ^ (l16 & 7); \
  const u16* Agl = Ablk + (size_t)(w*32 + r8)*KS + (size_t)((c8 ^ r8)*8); \
  const u16* Bgl = Bblk + (size_t)(w*32 + r8)*KS + (size_t)((c8 ^ r8)*8); \
  u16* sAl = sA + w*2048; \
  u16* sBl = sB + w*2048; \
  const u16* paA0 = sA + (wm + l16)*64 + p0*8; \
  const u16* paA1 = sA + (wm + l16)*64 + (p0^4)*8; \
  const u16* paB0 = sB + (wn + l16)*64 + p0*8; \
  const u16* paB1 = sB + (wn + l16)*64 + (p0^4)*8;

#define GLDS8(K0) do { \
  const u16* ga_ = Agl + (K0); \
  const u16* gb_ = Bgl + (K0); \
  GLD1(ga_,         sAl);        GLD1(ga_ +  8*KS, sAl +  512); \
  GLD1(ga_ + 16*KS, sAl + 1024); GLD1(ga_ + 24*KS, sAl + 1536); \
  GLD1(gb_,         sBl);        GLD1(gb_ +  8*KS, sBl +  512); \
  GLD1(gb_ + 16*KS, sBl + 1024); GLD1(gb_ + 24*KS, sBl + 1536); \
} while(0)

#define KKSTEP(PA, PB) do { \
  bf16x8 a0 = *(const bf16x8*)(PA); \
  bf16x8 a1 = *(const bf16x8*)((PA) + 1024); \
  bf16x8 a2 = *(const bf16x8*)((PA) + 2048); \
  bf16x8 a3 = *(const bf16x8*)((PA) + 3072); \
  bf16x8 b0 = *(const bf16x8*)(PB); \
  bf16x8 b1 = *(const bf16x8*)((PB) + 1024); \
  bf16x8 b2 = *(const bf16x8*)((PB) + 2048); \
  bf16x8 b3 = *(const bf16x8*)((PB) + 3072); \
  acc00 = MFMA(a0,b0,acc00,0,0,0); acc01 = MFMA(a0,b1,acc01,0,0,0); \
  acc02 = MFMA(a0,b2,acc02,0,0,0); acc03 = MFMA(a0,b3,acc03,0,0,0); \
  acc10 = MFMA(a1,b0,acc10,0,0,0); acc11 = MFMA(a1,b1,acc11,0,0,0); \
  acc12 = MFMA(a1,b2,acc12,0,0,0); acc13 = MFMA(a1,b3,acc13,0,0,0); \
  acc20 = MFMA(a2,b0,acc20,0,0,0); acc21 = MFMA(a2,b1,acc21,0,0,0); \
  acc22 = MFMA(a2,b2,acc22,0,0,0); acc23 = MFMA(a2,b3,acc23,0,0,0); \
  acc30 = MFMA(a3,b0,acc30,0,0,0); acc31 = MFMA(a3,b1,acc31,0,0,0); \
  acc32 = MFMA(a3,b2,acc32,0,0,0); acc33 = MFMA(a3,b3,acc33,0,0,0); \
} while(0)

#define KLOOP do { \
  for (int k0 = 0; k0 < KLEN; k0 += 64){ \
    __syncthreads(); \
    GLDS8(k0); \
    __syncthreads(); \
    KKSTEP(paA0, paB0); \
    KKSTEP(paA1, paB1); \
  } } while(0)

template<int KLEN, int KS, bool TRANSC>
static __device__ __forceinline__ void gemm128_core(
    const u16* __restrict__ Ablk, const u16* __restrict__ Bblk,
    const float* __restrict__ bias, u16* __restrict__ C,
    int mb, int nb, u16* sA, u16* sB)
{
  CORE_SETUP
  DECL_ACC
  KLOOP;
  int cb = nb*128 + wn + l16;
  float bb0=0.f, bb1=0.f, bb2=0.f, bb3=0.f;
  if (bias){ bb0=bias[cb]; bb1=bias[cb+16]; bb2=bias[cb+32]; bb3=bias[cb+48]; }
  if constexpr (!TRANSC) {
#define GEPI(IM,A0,A1,A2,A3) do { \
  int r0_ = mb*128 + wm + (IM)*16 + quad*4; \
  _Pragma("unroll") \
  for (int j=0;j<4;j++){ \
    C[(size_t)(r0_+j)*768 + cb     ] = f2bf(A0[j]+bb0); \
    C[(size_t)(r0_+j)*768 + cb + 16] = f2bf(A1[j]+bb1); \
    C[(size_t)(r0_+j)*768 + cb + 32] = f2bf(A2[j]+bb2); \
    C[(size_t)(r0_+j)*768 + cb + 48] = f2bf(A3[j]+bb3); \
  } } while(0)
    GEPI(0, acc00,acc01,acc02,acc03);
    GEPI(1, acc10,acc11,acc12,acc13);
    GEPI(2, acc20,acc21,acc22,acc23);
    GEPI(3, acc30,acc31,acc32,acc33);
#undef GEPI
  } else {
#define GEPT(IM,A0,A1,A2,A3) do { \
  int t0_ = wm + (IM)*16 + quad*4; \
  u16x4 p0_ = {f2bf(A0[0]+bb0),f2bf(A0[1]+bb0),f2bf(A0[2]+bb0),f2bf(A0[3]+bb0)}; \
  u16x4 p1_ = {f2bf(A1[0]+bb1),f2bf(A1[1]+bb1),f2bf(A1[2]+bb1),f2bf(A1[3]+bb1)}; \
  u16x4 p2_ = {f2bf(A2[0]+bb2),f2bf(A2[1]+bb2),f2bf(A2[2]+bb2),f2bf(A2[3]+bb2)}; \
  u16x4 p3_ = {f2bf(A3[0]+bb3),f2bf(A3[1]+bb3),f2bf(A3[2]+bb3),f2bf(A3[3]+bb3)}; \
  *(u16x4*)(C + (size_t)(cb     )*128 + t0_) = p0_; \
  *(u16x4*)(C + (size_t)(cb + 16)*128 + t0_) = p1_; \
  *(u16x4*)(C + (size_t)(cb + 32)*128 + t0_) = p2_; \
  *(u16x4*)(C + (size_t)(cb + 48)*128 + t0_) = p3_; \
} while(0)
    GEPT(0, acc00,acc01,acc02,acc03);
    GEPT(1, acc10,acc11,acc12,acc13);
    GEPT(2, acc20,acc21,acc22,acc23);
    GEPT(3, acc30,acc31,acc32,acc33);
#undef GEPT
  }
}

// ------- prep: conversions (0..7727) + 2 transposes (7728..8879) +
// ------- Mt = Wq.Wk^T MFMA GEMM (8880..8915, fp32 inline convert) +
// ------- wr=Wk.bq (8916..8921) + c2=Wq.bk (8922..8927) + bkbq (8928) --------
__global__ __launch_bounds__(256) void prep(
    const float* __restrict__ etok, u16* __restrict__ entb,
    const float* __restrict__ mtok, u16* __restrict__ menb,
    const float* __restrict__ ecls, u16* __restrict__ eclsb,
    const float* __restrict__ Wv, const float* __restrict__ Wc,
    u16* __restrict__ wvt, u16* __restrict__ wct,
    const float* __restrict__ Wq, const float* __restrict__ Wk,
    u16* __restrict__ mtb,
    const float* __restrict__ bq, const float* __restrict__ bk,
    float* __restrict__ wrb, float* __restrict__ c2b)
{
  __shared__ __align__(16) u16 shm[2*128*72];   // 36 KB, aliased per branch
  int blk = blockIdx.x;
  int tid = threadIdx.x;
  if (blk < 7728){
    int i = blk * 256 + tid;
    const float* s; u16* d; int off;
    if (i < 1572864)      { s=etok; d=entb; off=i; }
    else if (i < 1966080) { s=mtok; d=menb; off=i-1572864; }
    else                  { s=ecls; d=eclsb; off=i-1966080; }
    const float4* s4 = (const float4*)s;
    float4 a = s4[(size_t)off*2], b = s4[(size_t)off*2+1];
    u16x8 r;
    r[0]=f2bf(a.x); r[1]=f2bf(a.y); r[2]=f2bf(a.z); r[3]=f2bf(a.w);
    r[4]=f2bf(b.x); r[5]=f2bf(b.y); r[6]=f2bf(b.z); r[7]=f2bf(b.w);
    *(u16x8*)(d + (size_t)off*8) = r;
  } else if (blk < 8880){
    int n = blk - 7728;
    int z = n / 576, rem = n % 576;
    const float* s = z ? Wc : Wv;
    u16*         d = z ? wct : wvt;
    float* t = (float*)shm;       // [32][33]
    int bx = (rem % 24) * 32, by = (rem / 24) * 32;
    int tx = tid & 31, ty = (tid >> 5) * 4;
    for (int i=0;i<4;i++)
      t[(ty+i)*33 + tx] = s[(size_t)(by+ty+i)*768 + bx+tx];
    __syncthreads();
    for (int i=0;i<4;i++)
      d[(size_t)(bx+ty+i)*768 + by+tx] = f2bf(t[tx*33 + ty+i]);
  } else if (blk < 8916){
    // Mt[d][d'] = sum_h Wq[d,h]*Wk[d',h]; A=Wq, Bt=Wk, stride-72 LDS core
    int n = blk - 8880; int mbq = n/6, nbq = n%6;
    u16* tA = shm; u16* tB = shm + 128*72;
    int lane = tid & 63, w = tid >> 6;
    int wm = (w >> 1) * 64, wn = (w & 1) * 64;
    int quad = lane >> 4, l16 = lane & 15;
    int sr = tid >> 3, sc = (tid & 7) * 8;
    const float* Ag = Wq + (size_t)(mbq*128+sr)*768 + sc;
    const float* Bg = Wk + (size_t)(nbq*128+sr)*768 + sc;
    u16* tAp = tA + sr*72 + sc;
    u16* tBp = tB + sr*72 + sc;
    DECL_ACC
    for (int k0=0;k0<768;k0+=64){
      __syncthreads();
#define STG(G) do { \
      float4 xa0=*(const float4*)(Ag+(G)*32*768+k0), xa1=*(const float4*)(Ag+(G)*32*768+k0+4); \
      float4 xb0=*(const float4*)(Bg+(G)*32*768+k0), xb1=*(const float4*)(Bg+(G)*32*768+k0+4); \
      u16x8 ra={f2bf(xa0.x),f2bf(xa0.y),f2bf(xa0.z),f2bf(xa0.w), \
                f2bf(xa1.x),f2bf(xa1.y),f2bf(xa1.z),f2bf(xa1.w)}; \
      u16x8 rb={f2bf(xb0.x),f2bf(xb0.y),f2bf(xb0.z),f2bf(xb0.w), \
                f2bf(xb1.x),f2bf(xb1.y),f2bf(xb1.z),f2bf(xb1.w)}; \
      *(u16x8*)(tAp+(G)*32*72)=ra; *(u16x8*)(tBp+(G)*32*72)=rb; \
      } while(0)
      STG(0); STG(1); STG(2); STG(3);
#undef STG
      __syncthreads();
#define KK72(KB) do { \
      const u16* pa_=tA+(wm+l16)*72+(KB)+quad*8; \
      const u16* pb_=tB+(wn+l16)*72+(KB)+quad*8; \
      bf16x8 a0=*(const bf16x8*)(pa_),      a1=*(const bf16x8*)(pa_+16*72); \
      bf16x8 a2=*(const bf16x8*)(pa_+32*72),a3=*(const bf16x8*)(pa_+48*72); \
      bf16x8 b0=*(const bf16x8*)(pb_),      b1=*(const bf16x8*)(pb_+16*72); \
      bf16x8 b2=*(const bf16x8*)(pb_+32*72),b3=*(const bf16x8*)(pb_+48*72); \
      acc00=MFMA(a0,b0,acc00,0,0,0); acc01=MFMA(a0,b1,acc01,0,0,0); \
      acc02=MFMA(a0,b2,acc02,0,0,0); acc03=MFMA(a0,b3,acc03,0,0,0); \
      acc10=MFMA(a1,b0,acc10,0,0,0); acc11=MFMA(a1,b1,acc11,0,0,0); \
      acc12=MFMA(a1,b2,acc12,0,0,0); acc13=MFMA(a1,b3,acc13,0,0,0); \
      acc20=MFMA(a2,b0,acc20,0,0,0); acc21=MFMA(a2,b1,acc21,0,0,0); \
      acc22=MFMA(a2,b2,acc22,0,0,0); acc23=MFMA(a2,b3,acc23,0,0,0); \
      acc30=MFMA(a3,b0,acc30,0,0,0); acc31=MFMA(a3,b1,acc31,0,0,0); \
      acc32=MFMA(a3,b2,acc32,0,0,0); acc33=MFMA(a3,b3,acc33,0,0,0); \
      } while(0)
      KK72(0); KK72(32);
#undef KK72
    }
    int cb = nbq*128 + wn + l16;
#define GEPM(IM,A0,A1,A2,A3) do { \
    int r0_ = mbq*128 + wm + (IM)*16 + quad*4; \
    _Pragma("unroll") \
    for (int j=0;j<4;j++){ \
      mtb[(size_t)(r0_+j)*768 + cb     ] = f2bf(A0[j]); \
      mtb[(size_t)(r0_+j)*768 + cb + 16] = f2bf(A1[j]); \
      mtb[(size_t)(r0_+j)*768 + cb + 32] = f2bf(A2[j]); \
      mtb[(size_t)(r0_+j)*768 + cb + 48] = f2bf(A3[j]); \
    } } while(0)
    GEPM(0, acc00,acc01,acc02,acc03);
    GEPM(1, acc10,acc11,acc12,acc13);
    GEPM(2, acc20,acc21,acc22,acc23);
    GEPM(3, acc30,acc31,acc32,acc33);
#undef GEPM
  } else if (blk < 8928){
    // wr[d']=Wk[d',:].bq (blocks 0..5) ; c2[d]=Wq[d,:].bk (blocks 6..11)
    int n = blk - 8916;
    const float* M; const float* v; float* o;
    int j;
    if (n < 6){ M=Wk; v=bq; o=wrb; j=n; } else { M=Wq; v=bk; o=c2b; j=n-6; }
    int rr = tid >> 1, row = j*128 + rr;
    const float4* p = (const float4*)(M + (size_t)row*768 + (tid&1)*384);
    const float4* q = (const float4*)(v + (tid&1)*384);
    float s = 0.f;
    #pragma unroll 8
    for (int i=0;i<96;i++){
      float4 a=p[i], c=q[i];
      s += a.x*c.x + a.y*c.y + a.z*c.z + a.w*c.w;
    }
    s += __shfl_xor(s, 1);
    if (!(tid&1)) o[row] = s;
  } else {
    // bkbq scalar -> wrb[768]
    float s = 0.f;
    for (int i=tid;i<768;i+=256) s += bk[i]*bq[i];
    #pragma unroll
    for (int d2=1; d2<64; d2<<=1) s += __shfl_xor(s,d2);
    float* red = (float*)shm;
    int lane = tid & 63, w = tid >> 6;
    if (lane==0) red[w]=s;
    __syncthreads();
    if (tid==0) wrb[768] = red[0]+red[1]+red[2]+red[3];
  }
}

// ------- proj: V(->vtb transposed) y0..5 | G=men.Mt^T+c2 y6..11 | cls y12 |
// ------- rbias = men.wr + bkbq  y13 ------------------------------------------------
__global__ __launch_bounds__(256, 1) void proj(
    const u16* __restrict__ men, const u16* __restrict__ eclsb,
    const u16* __restrict__ wvt, const u16* __restrict__ wct,
    const u16* __restrict__ mtb,
    const float* __restrict__ bv, const float* __restrict__ bc,
    const float* __restrict__ c2b, const float* __restrict__ wrb,
    u16* __restrict__ vtb, u16* __restrict__ gtb, u16* __restrict__ clsb,
    float* __restrict__ rbias)
{
  __shared__ __align__(16) u16 sA[128*64];
  __shared__ __align__(16) u16 sB[128*64];
  int y = blockIdx.y, mb = blockIdx.x;
  if (y < 6){
    gemm128_core<768,768,true>(men + (size_t)mb*128*768, wvt + (size_t)y*128*768,
                               bv, vtb + (size_t)mb*98304, mb, y, sA, sB);
  } else if (y < 12){
    gemm128_core<768,768,false>(men + (size_t)mb*128*768, mtb + (size_t)(y-6)*128*768,
                                c2b, gtb, mb, y-6, sA, sB);
  } else if (y == 12){
    if (mb >= 6) return;
    gemm128_core<768,768,false>(eclsb, wct + (size_t)mb*128*768, bc, clsb, 0, mb, sA, sB);
  } else {
    int tid = threadIdx.x;
    int rr = tid >> 1, row = mb*128 + rr;
    const u16* p = men + (size_t)row*768 + (tid&1)*384;
    const float* q = wrb + (tid&1)*384;
    float s = 0.f;
    #pragma unroll 8
    for (int i=0;i<48;i++){
      u16x8 v = *(const u16x8*)(p + i*8);
      s += bf2f(v[0])*q[i*8]   + bf2f(v[1])*q[i*8+1]
         + bf2f(v[2])*q[i*8+2] + bf2f(v[3])*q[i*8+3]
         + bf2f(v[4])*q[i*8+4] + bf2f(v[5])*q[i*8+5]
         + bf2f(v[6])*q[i*8+6] + bf2f(v[7])*q[i*8+7];
    }
    s += __shfl_xor(s, 1);
    if (!(tid&1)) rbias[row] = s + wrb[768];
  }
}

// ------- attnk: 2 e-tiles per block (256x128 scores), per (b,epair) ----------------
// Row softmax fully in-wave (each wave owns full 128-col rows); no-max softmax
// (scores ~N(0,1)); column sums -> ptbf[b][e][t] bf16 /128.
__global__ __launch_bounds__(256, 1) void attnk(
    const u16* __restrict__ ent, const u16* __restrict__ gt,
    const float* __restrict__ rbias, u16* __restrict__ ptbf)
{
  __shared__ __align__(16) u16 sA[256*64];   // 32 KB (2 e-tiles)
  __shared__ __align__(16) u16 sB[128*64];   // 16 KB
  __shared__ float rbuf[512];
  int bi = blockIdx.x;          // b*64 + epair  (XCD=bi%8 -> fixed 16 ent tiles/XCD)
  int b = bi >> 6, ep = bi & 63;
  const u16* Ablk = ent + (size_t)ep * 256 * 768;
  const u16* Bblk = gt  + (size_t)b * 128 * 768;
  int tid = threadIdx.x;
  int lane = tid & 63, w = tid >> 6;
  int quad = lane >> 4, l16 = lane & 15;
  int r8 = lane >> 3, c8 = lane & 7;
  int p0 = quad ^ (l16 & 7);
  const u16* Agl = Ablk + (size_t)(w*64 + r8)*768 + (size_t)((c8 ^ r8)*8);
  const u16* Bgl = Bblk + (size_t)(w*32 + r8)*768 + (size_t)((c8 ^ r8)*8);
  u16* sAl = sA + w*4096;
  u16* sBl = sB + w*2048;
  const u16* paA0 = sA + (w*64 + l16)*64 + p0*8;
  const u16* paA1 = sA + (w*64 + l16)*64 + (p0^4)*8;
  const u16* paB0 = sB + l16*64 + p0*8;
  const u16* paB1 = sB + l16*64 + (p0^4)*8;
  f32x4 acc00={},acc01={},acc02={},acc03={},acc04={},acc05={},acc06={},acc07={},
        acc10={},acc11={},acc12={},acc13={},acc14={},acc15={},acc16={},acc17={},
        acc20={},acc21={},acc22={},acc23={},acc24={},acc25={},acc26={},acc27={},
        acc30={},acc31={},acc32={},acc33={},acc34={},acc35={},acc36={},acc37={};
#define AKH(PA, PB) do { \
  bf16x8 b0 = *(const bf16x8*)(PB); \
  bf16x8 b1 = *(const bf16x8*)((PB) + 1024); \
  bf16x8 b2 = *(const bf16x8*)((PB) + 2048); \
  bf16x8 b3 = *(const bf16x8*)((PB) + 3072); \
  bf16x8 b4 = *(const bf16x8*)((PB) + 4096); \
  bf16x8 b5 = *(const bf16x8*)((PB) + 5120); \
  bf16x8 b6 = *(const bf16x8*)((PB) + 6144); \
  bf16x8 b7 = *(const bf16x8*)((PB) + 7168); \
  bf16x8 a_; \
  a_ = *(const bf16x8*)(PA); \
  acc00=MFMA(a_,b0,acc00,0,0,0); acc01=MFMA(a_,b1,acc01,0,0,0); \
  acc02=MFMA(a_,b2,acc02,0,0,0); acc03=MFMA(a_,b3,acc03,0,0,0); \
  acc04=MFMA(a_,b4,acc04,0,0,0); acc05=MFMA(a_,b5,acc05,0,0,0); \
  acc06=MFMA(a_,b6,acc06,0,0,0); acc07=MFMA(a_,b7,acc07,0,0,0); \
  a_ = *(const bf16x8*)((PA) + 1024); \
  acc10=MFMA(a_,b0,acc10,0,0,0); acc11=MFMA(a_,b1,acc11,0,0,0); \
  acc12=MFMA(a_,b2,acc12,0,0,0); acc13=MFMA(a_,b3,acc13,0,0,0); \
  acc14=MFMA(a_,b4,acc14,0,0,0); acc15=MFMA(a_,b5,acc15,0,0,0); \
  acc16=MFMA(a_,b6,acc16,0,0,0); acc17=MFMA(a_,b7,acc17,0,0,0); \
  a_ = *(const bf16x8*)((PA) + 2048); \
  acc20=MFMA(a_,b0,acc20,0,0,0); acc21=MFMA(a_,b1,acc21,0,0,0); \
  acc22=MFMA(a_,b2,acc22,0,0,0); acc23=MFMA(a_,b3,acc23,0,0,0); \
  acc24=MFMA(a_,b4,acc24,0,0,0); acc25=MFMA(a_,b5,acc25,0,0,0); \
  acc26=MFMA(a_,b6,acc26,0,0,0); acc27=MFMA(a_,b7,acc27,0,0,0); \
  a_ = *(const bf16x8*)((PA) + 3072); \
  acc30=MFMA(a_,b0,acc30,0,0,0); acc31=MFMA(a_,b1,acc31,0,0,0); \
  acc32=MFMA(a_,b2,acc32,0,0,0); acc33=MFMA(a_,b3,acc33,0,0,0); \
  acc34=MFMA(a_,b4,acc34,0,0,0); acc35=MFMA(a_,b5,acc35,0,0,0); \
  acc36=MFMA(a_,b6,acc36,0,0,0); acc37=MFMA(a_,b7,acc37,0,0,0); \
} while(0)
  for (int k0 = 0; k0 < 768; k0 += 64){
    __syncthreads();
    {
      const u16* ga_ = Agl + k0;
      const u16* gb_ = Bgl + k0;
      GLD1(ga_,          sAl);        GLD1(ga_ +  8*768, sAl +  512);
      GLD1(ga_ + 16*768, sAl + 1024); GLD1(ga_ + 24*768, sAl + 1536);
      GLD1(ga_ + 32*768, sAl + 2048); GLD1(ga_ + 40*768, sAl + 2560);
      GLD1(ga_ + 48*768, sAl + 3072); GLD1(ga_ + 56*768, sAl + 3584);
      GLD1(gb_,          sBl);        GLD1(gb_ +  8*768, sBl +  512);
      GLD1(gb_ + 16*768, sBl + 1024); GLD1(gb_ + 24*768, sBl + 1536);
    }
    __syncthreads();
    AKH(paA0, paB0);
    AKH(paA1, paB1);
  }
#undef AKH
  // softmax over cols (t), fully in-wave per row; fold scale+rbias into exp2 arg
  const float c1 = 0.036084391824351615f * 1.4426950408889634f;
  float rs0 = rbias[b*128        + l16] * c1;
  float rs1 = rbias[b*128 +  16  + l16] * c1;
  float rs2 = rbias[b*128 +  32  + l16] * c1;
  float rs3 = rbias[b*128 +  48  + l16] * c1;
  float rs4 = rbias[b*128 +  64  + l16] * c1;
  float rs5 = rbias[b*128 +  80  + l16] * c1;
  float rs6 = rbias[b*128 +  96  + l16] * c1;
  float rs7 = rbias[b*128 + 112  + l16] * c1;
  float cs0=0.f,cs1=0.f,cs2=0.f,cs3=0.f,cs4=0.f,cs5=0.f,cs6=0.f,cs7=0.f;
#define EXPROW(A0,A1,A2,A3,A4,A5,A6,A7) do { \
  _Pragma("unroll") \
  for (int j=0;j<4;j++){ \
    float e0 = exp2f(fmaf(A0[j], c1, rs0)); \
    float e1 = exp2f(fmaf(A1[j], c1, rs1)); \
    float e2 = exp2f(fmaf(A2[j], c1, rs2)); \
    float e3 = exp2f(fmaf(A3[j], c1, rs3)); \
    float e4 = exp2f(fmaf(A4[j], c1, rs4)); \
    float e5 = exp2f(fmaf(A5[j], c1, rs5)); \
    float e6 = exp2f(fmaf(A6[j], c1, rs6)); \
    float e7 = exp2f(fmaf(A7[j], c1, rs7)); \
    float s_ = ((e0+e1)+(e2+e3)) + ((e4+e5)+(e6+e7)); \
    s_ += __shfl_xor(s_,1); s_ += __shfl_xor(s_,2); \
    s_ += __shfl_xor(s_,4); s_ += __shfl_xor(s_,8); \
    float inv = __builtin_amdgcn_rcpf(s_); \
    cs0 = fmaf(e0,inv,cs0); cs1 = fmaf(e1,inv,cs1); \
    cs2 = fmaf(e2,inv,cs2); cs3 = fmaf(e3,inv,cs3); \
    cs4 = fmaf(e4,inv,cs4); cs5 = fmaf(e5,inv,cs5); \
    cs6 = fmaf(e6,inv,cs6); cs7 = fmaf(e7,inv,cs7); \
  } } while(0)
  EXPROW(acc00,acc01,acc02,acc03,acc04,acc05,acc06,acc07);
  EXPROW(acc10,acc11,acc12,acc13,acc14,acc15,acc16,acc17);
  EXPROW(acc20,acc21,acc22,acc23,acc24,acc25,acc26,acc27);
  EXPROW(acc30,acc31,acc32,acc33,acc34,acc35,acc36,acc37);
#undef EXPROW
  // column sums over this wave's 64 rows: reduce across quads
  cs0 += __shfl_xor(cs0,16); cs0 += __shfl_xor(cs0,32);
  cs1 += __shfl_xor(cs1,16); cs1 += __shfl_xor(cs1,32);
  cs2 += __shfl_xor(cs2,16); cs2 += __shfl_xor(cs2,32);
  cs3 += __shfl_xor(cs3,16); cs3 += __shfl_xor(cs3,32);
  cs4 += __shfl_xor(cs4,16); cs4 += __shfl_xor(cs4,32);
  cs5 += __shfl_xor(cs5,16); cs5 += __shfl_xor(cs5,32);
  cs6 += __shfl_xor(cs6,16); cs6 += __shfl_xor(cs6,32);
  cs7 += __shfl_xor(cs7,16); cs7 += __shfl_xor(cs7,32);
  if (quad == 0){
    rbuf[w*128        + l16] = cs0;
    rbuf[w*128 +  16  + l16] = cs1;
    rbuf[w*128 +  32  + l16] = cs2;
    rbuf[w*128 +  48  + l16] = cs3;
    rbuf[w*128 +  64  + l16] = cs4;
    rbuf[w*128 +  80  + l16] = cs5;
    rbuf[w*128 +  96  + l16] = cs6;
    rbuf[w*128 + 112  + l16] = cs7;
  }
  __syncthreads();
  {
    int half = tid >> 7, t = tid & 127;           // waves {0,1}->e0, {2,3}->e1
    float v = rbuf[half*256 + t] + rbuf[half*256 + 128 + t];
    int e = ep*2 + half;
    ptbf[((size_t)b*128 + e)*128 + t] = f2bf(v * 0.0078125f);
  }
}

// ---------------- ctx2: ctx[b][e][h] = ptot_b[e][t] @ Vt_b[h][t]^T, K=128 ------------
__global__ __launch_bounds__(256, 1) void ctx2(
    const u16* __restrict__ ptbf, const u16* __restrict__ vtb,
    u16* __restrict__ ctxb)
{
  __shared__ __align__(16) u16 sA[128*64];
  __shared__ __align__(16) u16 sB[128*64];
  int b = blockIdx.y, nb = blockIdx.x;
  gemm128_core<128,128,false>(ptbf + (size_t)b*16384,
                              vtb + (size_t)b*98304 + (size_t)nb*16384,
                              nullptr, ctxb + (size_t)b*98304, 0, nb, sA, sB);
}

// ---------------- fin: LN(ctx) + dual matching scores, one block per (b,e) -----------
__global__ __launch_bounds__(256) void fin(
    const u16* __restrict__ ctxb, const u16* __restrict__ clsfc,
    const float* __restrict__ ecls, const float* __restrict__ mcls,
    const float* __restrict__ lng, const float* __restrict__ lnb,
    float* __restrict__ out)
{
  int bi = blockIdx.x;          // b*128 + e
  int b = bi >> 7, e = bi & 127;
  int tid = threadIdx.x;
  int lane = tid & 63, w = tid >> 6;
  __shared__ float redbuf[8];
  const u16* cr = ctxb + ((size_t)b*128 + e)*768;
  float a0 = bf2f(cr[tid]), a1 = bf2f(cr[tid+256]), a2 = bf2f(cr[tid+512]);
  float s1 = a0+a1+a2;
  float s2 = a0*a0 + a1*a1 + a2*a2;
  #pragma unroll
  for (int d2=1; d2<64; d2<<=1){ s1 += __shfl_xor(s1,d2); s2 += __shfl_xor(s2,d2); }
  if (lane==0){ redbuf[w]=s1; redbuf[4+w]=s2; }
  __syncthreads();
  s1 = redbuf[0]+redbuf[1]+redbuf[2]+redbuf[3];
  s2 = redbuf[4]+redbuf[5]+redbuf[6]+redbuf[7];
  float mu = s1 * (1.0f/768.0f);
  float var = s2 * (1.0f/768.0f) - mu*mu;
  float rstd = rsqrtf(var + 1e-5f);
  float dd = 0.f;
  {
    int h = tid;
    float y = (a0-mu)*rstd*lng[h] + lnb[h];
    dd += y * bf2f(clsfc[e*768+h]) + mcls[b*768+h]*ecls[e*768+h];
    h = tid + 256;
    y = (a1-mu)*rstd*lng[h] + lnb[h];
    dd += y * bf2f(clsfc[e*768+h]) + mcls[b*768+h]*ecls[e*768+h];
    h = tid + 512;
    y = (a2-mu)*rstd*lng[h] + lnb[h];
    dd += y * bf2f(clsfc[e*768+h]) + mcls[b*768+h]*ecls[e*768+h];
  }
  #pragma unroll
  for (int d2=1; d2<64; d2<<=1) dd += __shfl_xor(dd,d2);
  __syncthreads();
  if (lane==0) redbuf[w] = dd;
  __syncthreads();
  if (tid==0) out[bi] = 0.5f * (redbuf[0]+redbuf[1]+redbuf[2]+redbuf[3]);
}

extern "C" void kernel_launch(void* const* d_in, const int* in_sizes, int n_in,
                              void* d_out, int out_size, void* d_ws, size_t ws_size,
                              hipStream_t stream)
{
  (void)in_sizes; (void)n_in; (void)out_size; (void)ws_size;
  const float* ecls = (const float*)d_in[0];
  const float* etok = (const float*)d_in[1];
  const float* mcls = (const float*)d_in[2];
  const float* mtok = (const float*)d_in[3];
  const float* Wq   = (const float*)d_in[4];
  const float* bq   = (const float*)d_in[5];
  const float* Wk   = (const float*)d_in[6];
  const float* bk   = (const float*)d_in[7];
  const float* Wv   = (const float*)d_in[8];
  const float* bv   = (const float*)d_in[9];
  const float* Wc   = (const float*)d_in[10];
  const float* bc   = (const float*)d_in[11];
  const float* lng  = (const float*)d_in[12];
  const float* lnb  = (const float*)d_in[13];
  float* out = (float*)d_out;
  char* ws = (char*)d_ws;

  // workspace layout (bytes)
  u16* ent_bf  = (u16*)(ws + 0);          // 16384x768 bf16 = 25165824
  u16* men_bf  = (u16*)(ws + 25165824);   //  4096x768 bf16 =  6291456
  u16* ecls_bf = (u16*)(ws + 31457280);   //   128x768 bf16 =   196608
  u16* wvt     = (u16*)(ws + 31653888);   //   768x768 bf16 =  1179648 (transposed)
  u16* wct     = (u16*)(ws + 32833536);   //   768x768 bf16
  u16* mtb     = (u16*)(ws + 34013184);   //   768x768 bf16 (Mt = Wq.Wk^T)
  u16* vtb     = (u16*)(ws + 35192832);   //  32x768x128 bf16 = 6291456 (V^T per b)
  u16* clsb    = (u16*)(ws + 41484288);   //   128x768 bf16 =   196608
  u16* gtb     = (u16*)(ws + 41680896);   //  4096x768 bf16 =  6291456
  float* rbias = (float*)(ws + 47972352); //  4096 f32      =    16384
  float* wrb   = (float*)(ws + 47988736); //  769 f32 (wr + bkbq)
  float* c2b   = (float*)(ws + 47992832); //  768 f32
  u16* ptbf    = (u16*)(ws + 47996928);   //  32x128x128 bf16 = 1048576
  u16* ctxb    = (u16*)(ws + 49045504);   //  32x128x768 bf16 = 6291456

  prep<<<8929, 256, 0, stream>>>(etok, ent_bf, mtok, men_bf, ecls, ecls_bf,
                                 Wv, Wc, wvt, wct, Wq, Wk, mtb,
                                 bq, bk, wrb, c2b);
  proj<<<dim3(32,14), 256, 0, stream>>>(men_bf, ecls_bf, wvt, wct, mtb,
                                        bv, bc, c2b, wrb,
                                        vtb, gtb, clsb, rbias);
  attnk<<<2048, 256, 0, stream>>>(ent_bf, gtb, rbias, ptbf);
  ctx2<<<dim3(6,32), 256, 0, stream>>>(ptbf, vtb, ctxb);
  fin<<<4096, 256, 0, stream>>>(ctxb, clsb, ecls, mcls, lng, lnb, out);
}

// Round 9
// 299.105 us; speedup vs baseline: 1.2458x; 1.2458x over previous
//
#include <hip/hip_runtime.h>

typedef unsigned short u16;
typedef __bf16 bf16x8 __attribute__((ext_vector_type(8)));
typedef float f32x4 __attribute__((ext_vector_type(4)));
typedef u16 u16x8 __attribute__((ext_vector_type(8)));
typedef u16 u16x4 __attribute__((ext_vector_type(4)));

static __device__ __forceinline__ u16 f2bf(float x){
  unsigned u = __float_as_uint(x);
  u += 0x7fffu + ((u >> 16) & 1u);
  return (u16)(u >> 16);
}
static __device__ __forceinline__ float bf2f(u16 u){
  return __uint_as_float(((unsigned)u) << 16);
}

#define MFMA __builtin_amdgcn_mfma_f32_16x16x32_bf16

#define GLD1(GP, LP) __builtin_amdgcn_global_load_lds( \
    (const __attribute__((address_space(1))) unsigned int*)(GP), \
    (__attribute__((address_space(3))) unsigned int*)(LP), 16, 0, 0)

// ---- 16-acc core macros (named SSA vars only; arrays get memory-lowered) ----
#define DECL_ACC \
  f32x4 acc00={},acc01={},acc02={},acc03={}, \
        acc10={},acc11={},acc12={},acc13={}, \
        acc20={},acc21={},acc22={},acc23={}, \
        acc30={},acc31={},acc32={},acc33={};

#define CORE_SETUP \
  int tid = threadIdx.x; \
  int lane = tid & 63, w = tid >> 6; \
  int wm = (w >> 1) * 64, wn = (w & 1) * 64; \
  int quad = lane >> 4, l16 = lane & 15; \
  int r8 = lane >> 3, c8 = lane & 7; \
  int p0 = quad ^ (l16 & 7); \
  const u16* Agl = Ablk + (size_t)(w*32 + r8)*KS + (size_t)((c8 ^ r8)*8); \
  const u16* Bgl = Bblk + (size_t)(w*32 + r8)*KS + (size_t)((c8 ^ r8)*8); \
  u16* sAl = sA + w*2048; \
  u16* sBl = sB + w*2048; \
  const u16* paA0 = sA + (wm + l16)*64 + p0*8; \
  const u16* paA1 = sA + (wm + l16)*64 + (p0^4)*8; \
  const u16* paB0 = sB + (wn + l16)*64 + p0*8; \
  const u16* paB1 = sB + (wn + l16)*64 + (p0^4)*8;

#define GLDS8(K0) do { \
  const u16* ga_ = Agl + (K0); \
  const u16* gb_ = Bgl + (K0); \
  GLD1(ga_,         sAl);        GLD1(ga_ +  8*KS, sAl +  512); \
  GLD1(ga_ + 16*KS, sAl + 1024); GLD1(ga_ + 24*KS, sAl + 1536); \
  GLD1(gb_,         sBl);        GLD1(gb_ +  8*KS, sBl +  512); \
  GLD1(gb_ + 16*KS, sBl + 1024); GLD1(gb_ + 24*KS, sBl + 1536); \
} while(0)

#define KKSTEP(PA, PB) do { \
  bf16x8 a0 = *(const bf16x8*)(PA); \
  bf16x8 a1 = *(const bf16x8*)((PA) + 1024); \
  bf16x8 a2 = *(const bf16x8*)((PA) + 2048); \
  bf16x8 a3 = *(const bf16x8*)((PA) + 3072); \
  bf16x8 b0 = *(const bf16x8*)(PB); \
  bf16x8 b1 = *(const bf16x8*)((PB) + 1024); \
  bf16x8 b2 = *(const bf16x8*)((PB) + 2048); \
  bf16x8 b3 = *(const bf16x8*)((PB) + 3072); \
  acc00 = MFMA(a0,b0,acc00,0,0,0); acc01 = MFMA(a0,b1,acc01,0,0,0); \
  acc02 = MFMA(a0,b2,acc02,0,0,0); acc03 = MFMA(a0,b3,acc03,0,0,0); \
  acc10 = MFMA(a1,b0,acc10,0,0,0); acc11 = MFMA(a1,b1,acc11,0,0,0); \
  acc12 = MFMA(a1,b2,acc12,0,0,0); acc13 = MFMA(a1,b3,acc13,0,0,0); \
  acc20 = MFMA(a2,b0,acc20,0,0,0); acc21 = MFMA(a2,b1,acc21,0,0,0); \
  acc22 = MFMA(a2,b2,acc22,0,0,0); acc23 = MFMA(a2,b3,acc23,0,0,0); \
  acc30 = MFMA(a3,b0,acc30,0,0,0); acc31 = MFMA(a3,b1,acc31,0,0,0); \
  acc32 = MFMA(a3,b2,acc32,0,0,0); acc33 = MFMA(a3,b3,acc33,0,0,0); \
} while(0)

#define KLOOP do { \
  for (int k0 = 0; k0 < KLEN; k0 += 64){ \
    __syncthreads(); \
    GLDS8(k0); \
    __syncthreads(); \
    KKSTEP(paA0, paB0); \
    KKSTEP(paA1, paB1); \
  } } while(0)

template<int KLEN, int KS, bool TRANSC>
static __device__ __forceinline__ void gemm128_core(
    const u16* __restrict__ Ablk, const u16* __restrict__ Bblk,
    const float* __restrict__ bias, u16* __restrict__ C,
    int mb, int nb, u16* sA, u16* sB)
{
  CORE_SETUP
  DECL_ACC
  KLOOP;
  int cb = nb*128 + wn + l16;
  float bb0=0.f, bb1=0.f, bb2=0.f, bb3=0.f;
  if (bias){ bb0=bias[cb]; bb1=bias[cb+16]; bb2=bias[cb+32]; bb3=bias[cb+48]; }
  if constexpr (!TRANSC) {
#define GEPI(IM,A0,A1,A2,A3) do { \
  int r0_ = mb*128 + wm + (IM)*16 + quad*4; \
  _Pragma("unroll") \
  for (int j=0;j<4;j++){ \
    C[(size_t)(r0_+j)*768 + cb     ] = f2bf(A0[j]+bb0); \
    C[(size_t)(r0_+j)*768 + cb + 16] = f2bf(A1[j]+bb1); \
    C[(size_t)(r0_+j)*768 + cb + 32] = f2bf(A2[j]+bb2); \
    C[(size_t)(r0_+j)*768 + cb + 48] = f2bf(A3[j]+bb3); \
  } } while(0)
    GEPI(0, acc00,acc01,acc02,acc03);
    GEPI(1, acc10,acc11,acc12,acc13);
    GEPI(2, acc20,acc21,acc22,acc23);
    GEPI(3, acc30,acc31,acc32,acc33);
#undef GEPI
  } else {
#define GEPT(IM,A0,A1,A2,A3) do { \
  int t0_ = wm + (IM)*16 + quad*4; \
  u16x4 p0_ = {f2bf(A0[0]+bb0),f2bf(A0[1]+bb0),f2bf(A0[2]+bb0),f2bf(A0[3]+bb0)}; \
  u16x4 p1_ = {f2bf(A1[0]+bb1),f2bf(A1[1]+bb1),f2bf(A1[2]+bb1),f2bf(A1[3]+bb1)}; \
  u16x4 p2_ = {f2bf(A2[0]+bb2),f2bf(A2[1]+bb2),f2bf(A2[2]+bb2),f2bf(A2[3]+bb2)}; \
  u16x4 p3_ = {f2bf(A3[0]+bb3),f2bf(A3[1]+bb3),f2bf(A3[2]+bb3),f2bf(A3[3]+bb3)}; \
  *(u16x4*)(C + (size_t)(cb     )*128 + t0_) = p0_; \
  *(u16x4*)(C + (size_t)(cb + 16)*128 + t0_) = p1_; \
  *(u16x4*)(C + (size_t)(cb + 32)*128 + t0_) = p2_; \
  *(u16x4*)(C + (size_t)(cb + 48)*128 + t0_) = p3_; \
} while(0)
    GEPT(0, acc00,acc01,acc02,acc03);
    GEPT(1, acc10,acc11,acc12,acc13);
    GEPT(2, acc20,acc21,acc22,acc23);
    GEPT(3, acc30,acc31,acc32,acc33);
#undef GEPT
  }
}

// ------- prep: Mt = Wq.Wk^T (blocks 0..35, FIRST so the slow GEMM blocks
// ------- start early and hide under the conversion stream) + wr/c2 (36..47) +
// ------- bkbq (48) + conversions (49..7776) + 2 transposes (7777..8928) ------
__global__ __launch_bounds__(256) void prep(
    const float* __restrict__ etok, u16* __restrict__ entb,
    const float* __restrict__ mtok, u16* __restrict__ menb,
    const float* __restrict__ ecls, u16* __restrict__ eclsb,
    const float* __restrict__ Wv, const float* __restrict__ Wc,
    u16* __restrict__ wvt, u16* __restrict__ wct,
    const float* __restrict__ Wq, const float* __restrict__ Wk,
    u16* __restrict__ mtb,
    const float* __restrict__ bq, const float* __restrict__ bk,
    float* __restrict__ wrb, float* __restrict__ c2b)
{
  __shared__ __align__(16) u16 shm[2*128*72];   // 36 KB, aliased per branch
  int blk = blockIdx.x;
  int tid = threadIdx.x;
  if (blk < 36){
    // Mt[d][d'] = sum_h Wq[d,h]*Wk[d',h]; A=Wq, Bt=Wk, stride-72 LDS core
    int mbq = blk/6, nbq = blk%6;
    u16* tA = shm; u16* tB = shm + 128*72;
    int lane = tid & 63, w = tid >> 6;
    int wm = (w >> 1) * 64, wn = (w & 1) * 64;
    int quad = lane >> 4, l16 = lane & 15;
    int sr = tid >> 3, sc = (tid & 7) * 8;
    const float* Ag = Wq + (size_t)(mbq*128+sr)*768 + sc;
    const float* Bg = Wk + (size_t)(nbq*128+sr)*768 + sc;
    u16* tAp = tA + sr*72 + sc;
    u16* tBp = tB + sr*72 + sc;
    DECL_ACC
    for (int k0=0;k0<768;k0+=64){
      __syncthreads();
#define STG(G) do { \
      float4 xa0=*(const float4*)(Ag+(G)*32*768+k0), xa1=*(const float4*)(Ag+(G)*32*768+k0+4); \
      float4 xb0=*(const float4*)(Bg+(G)*32*768+k0), xb1=*(const float4*)(Bg+(G)*32*768+k0+4); \
      u16x8 ra={f2bf(xa0.x),f2bf(xa0.y),f2bf(xa0.z),f2bf(xa0.w), \
                f2bf(xa1.x),f2bf(xa1.y),f2bf(xa1.z),f2bf(xa1.w)}; \
      u16x8 rb={f2bf(xb0.x),f2bf(xb0.y),f2bf(xb0.z),f2bf(xb0.w), \
                f2bf(xb1.x),f2bf(xb1.y),f2bf(xb1.z),f2bf(xb1.w)}; \
      *(u16x8*)(tAp+(G)*32*72)=ra; *(u16x8*)(tBp+(G)*32*72)=rb; \
      } while(0)
      STG(0); STG(1); STG(2); STG(3);
#undef STG
      __syncthreads();
#define KK72(KB) do { \
      const u16* pa_=tA+(wm+l16)*72+(KB)+quad*8; \
      const u16* pb_=tB+(wn+l16)*72+(KB)+quad*8; \
      bf16x8 a0=*(const bf16x8*)(pa_),      a1=*(const bf16x8*)(pa_+16*72); \
      bf16x8 a2=*(const bf16x8*)(pa_+32*72),a3=*(const bf16x8*)(pa_+48*72); \
      bf16x8 b0=*(const bf16x8*)(pb_),      b1=*(const bf16x8*)(pb_+16*72); \
      bf16x8 b2=*(const bf16x8*)(pb_+32*72),b3=*(const bf16x8*)(pb_+48*72); \
      acc00=MFMA(a0,b0,acc00,0,0,0); acc01=MFMA(a0,b1,acc01,0,0,0); \
      acc02=MFMA(a0,b2,acc02,0,0,0); acc03=MFMA(a0,b3,acc03,0,0,0); \
      acc10=MFMA(a1,b0,acc10,0,0,0); acc11=MFMA(a1,b1,acc11,0,0,0); \
      acc12=MFMA(a1,b2,acc12,0,0,0); acc13=MFMA(a1,b3,acc13,0,0,0); \
      acc20=MFMA(a2,b0,acc20,0,0,0); acc21=MFMA(a2,b1,acc21,0,0,0); \
      acc22=MFMA(a2,b2,acc22,0,0,0); acc23=MFMA(a2,b3,acc23,0,0,0); \
      acc30=MFMA(a3,b0,acc30,0,0,0); acc31=MFMA(a3,b1,acc31,0,0,0); \
      acc32=MFMA(a3,b2,acc32,0,0,0); acc33=MFMA(a3,b3,acc33,0,0,0); \
      } while(0)
      KK72(0); KK72(32);
#undef KK72
    }
    int cb = nbq*128 + wn + l16;
#define GEPM(IM,A0,A1,A2,A3) do { \
    int r0_ = mbq*128 + wm + (IM)*16 + quad*4; \
    _Pragma("unroll") \
    for (int j=0;j<4;j++){ \
      mtb[(size_t)(r0_+j)*768 + cb     ] = f2bf(A0[j]); \
      mtb[(size_t)(r0_+j)*768 + cb + 16] = f2bf(A1[j]); \
      mtb[(size_t)(r0_+j)*768 + cb + 32] = f2bf(A2[j]); \
      mtb[(size_t)(r0_+j)*768 + cb + 48] = f2bf(A3[j]); \
    } } while(0)
    GEPM(0, acc00,acc01,acc02,acc03);
    GEPM(1, acc10,acc11,acc12,acc13);
    GEPM(2, acc20,acc21,acc22,acc23);
    GEPM(3, acc30,acc31,acc32,acc33);
#undef GEPM
  } else if (blk < 48){
    // wr[d']=Wk[d',:].bq (0..5) ; c2[d]=Wq[d,:].bk (6..11)
    int n = blk - 36;
    const float* M; const float* v; float* o;
    int j;
    if (n < 6){ M=Wk; v=bq; o=wrb; j=n; } else { M=Wq; v=bk; o=c2b; j=n-6; }
    int rr = tid >> 1, row = j*128 + rr;
    const float4* p = (const float4*)(M + (size_t)row*768 + (tid&1)*384);
    const float4* q = (const float4*)(v + (tid&1)*384);
    float s = 0.f;
    #pragma unroll 8
    for (int i=0;i<96;i++){
      float4 a=p[i], c=q[i];
      s += a.x*c.x + a.y*c.y + a.z*c.z + a.w*c.w;
    }
    s += __shfl_xor(s, 1);
    if (!(tid&1)) o[row] = s;
  } else if (blk == 48){
    // bkbq scalar -> wrb[768]
    float s = 0.f;
    for (int i=tid;i<768;i+=256) s += bk[i]*bq[i];
    #pragma unroll
    for (int d2=1; d2<64; d2<<=1) s += __shfl_xor(s,d2);
    float* red = (float*)shm;
    int lane = tid & 63, w = tid >> 6;
    if (lane==0) red[w]=s;
    __syncthreads();
    if (tid==0) wrb[768] = red[0]+red[1]+red[2]+red[3];
  } else if (blk < 7777){
    int i = (blk - 49) * 256 + tid;
    const float* s; u16* d; int off;
    if (i < 1572864)      { s=etok; d=entb; off=i; }
    else if (i < 1966080) { s=mtok; d=menb; off=i-1572864; }
    else                  { s=ecls; d=eclsb; off=i-1966080; }
    const float4* s4 = (const float4*)s;
    float4 a = s4[(size_t)off*2], b = s4[(size_t)off*2+1];
    u16x8 r;
    r[0]=f2bf(a.x); r[1]=f2bf(a.y); r[2]=f2bf(a.z); r[3]=f2bf(a.w);
    r[4]=f2bf(b.x); r[5]=f2bf(b.y); r[6]=f2bf(b.z); r[7]=f2bf(b.w);
    *(u16x8*)(d + (size_t)off*8) = r;
  } else {
    int n = blk - 7777;
    int z = n / 576, rem = n % 576;
    const float* s = z ? Wc : Wv;
    u16*         d = z ? wct : wvt;
    float* t = (float*)shm;       // [32][33]
    int bx = (rem % 24) * 32, by = (rem / 24) * 32;
    int tx = tid & 31, ty = (tid >> 5) * 4;
    for (int i=0;i<4;i++)
      t[(ty+i)*33 + tx] = s[(size_t)(by+ty+i)*768 + bx+tx];
    __syncthreads();
    for (int i=0;i<4;i++)
      d[(size_t)(bx+ty+i)*768 + by+tx] = f2bf(t[tx*33 + ty+i]);
  }
}

// ------- proj: V(->vtb transposed) y0..5 | G=men.Mt^T+c2 y6..11 | cls y12 |
// ------- rbias = men.wr + bkbq  y13 ------------------------------------------------
__global__ __launch_bounds__(256, 1) void proj(
    const u16* __restrict__ men, const u16* __restrict__ eclsb,
    const u16* __restrict__ wvt, const u16* __restrict__ wct,
    const u16* __restrict__ mtb,
    const float* __restrict__ bv, const float* __restrict__ bc,
    const float* __restrict__ c2b, const float* __restrict__ wrb,
    u16* __restrict__ vtb, u16* __restrict__ gtb, u16* __restrict__ clsb,
    float* __restrict__ rbias)
{
  __shared__ __align__(16) u16 sA[128*64];
  __shared__ __align__(16) u16 sB[128*64];
  int y = blockIdx.y, mb = blockIdx.x;
  if (y < 6){
    gemm128_core<768,768,true>(men + (size_t)mb*128*768, wvt + (size_t)y*128*768,
                               bv, vtb + (size_t)mb*98304, mb, y, sA, sB);
  } else if (y < 12){
    gemm128_core<768,768,false>(men + (size_t)mb*128*768, mtb + (size_t)(y-6)*128*768,
                                c2b, gtb, mb, y-6, sA, sB);
  } else if (y == 12){
    if (mb >= 6) return;
    gemm128_core<768,768,false>(eclsb, wct + (size_t)mb*128*768, bc, clsb, 0, mb, sA, sB);
  } else {
    int tid = threadIdx.x;
    int rr = tid >> 1, row = mb*128 + rr;
    const u16* p = men + (size_t)row*768 + (tid&1)*384;
    const float* q = wrb + (tid&1)*384;
    float s = 0.f;
    #pragma unroll 8
    for (int i=0;i<48;i++){
      u16x8 v = *(const u16x8*)(p + i*8);
      s += bf2f(v[0])*q[i*8]   + bf2f(v[1])*q[i*8+1]
         + bf2f(v[2])*q[i*8+2] + bf2f(v[3])*q[i*8+3]
         + bf2f(v[4])*q[i*8+4] + bf2f(v[5])*q[i*8+5]
         + bf2f(v[6])*q[i*8+6] + bf2f(v[7])*q[i*8+7];
    }
    s += __shfl_xor(s, 1);
    if (!(tid&1)) rbias[row] = s + wrb[768];
  }
}

// ------- attnk (r7 128x128 structure + K-phase rotation): per (b,e) ---------------
// S = etok_e . Gt_b^T + r, no-max softmax over cols(t), column sums -> ptbf.
// K-accumulation commutes, so each block starts its 12-chunk K loop at a
// rotated phase ((bi&3)*3) to decorrelate barrier-aligned L2 fetch bursts
// across blocks sharing a CU/XCD.
__global__ __launch_bounds__(256, 1) void attnk(
    const u16* __restrict__ ent, const u16* __restrict__ gt,
    const float* __restrict__ rbias, u16* __restrict__ ptbf)
{
  __shared__ __align__(16) u16 sA[128*64];
  __shared__ __align__(16) u16 sB[128*64];
  __shared__ float rbufA[256];  // column-sum halves
  __shared__ float rbufB[256];  // rowsum halves
  int bi = blockIdx.x;          // b*128 + e (XCD=bi%8 -> disjoint ent sets)
  int b = bi >> 7, e = bi & 127;
  const u16* Ablk = ent + (size_t)e * 128 * 768;
  const u16* Bblk = gt  + (size_t)b * 128 * 768;
  constexpr int KS = 768;
  CORE_SETUP
  DECL_ACC
  int ph = (bi & 3) * 3;
  for (int it = 0; it < 12; it++){
    int kidx = it + ph; if (kidx >= 12) kidx -= 12;
    int k0 = kidx << 6;
    __syncthreads();
    GLDS8(k0);
    __syncthreads();
    KKSTEP(paA0, paB0);
    KKSTEP(paA1, paB1);
  }
  // exp arg = (dot + rbias)*scale*log2e = dot*c1 + rbias*c1
  const float c1 = 0.036084391824351615f * 1.4426950408889634f;
  float rs0 = rbias[b*128 + wn      + l16] * c1;
  float rs1 = rbias[b*128 + wn + 16 + l16] * c1;
  float rs2 = rbias[b*128 + wn + 32 + l16] * c1;
  float rs3 = rbias[b*128 + wn + 48 + l16] * c1;
  // rows: r = wm + im*16 + quad*4 + j ; cols: c = wn + in*16 + l16
#define EXPSUM(IM,A0,A1,A2,A3) do { \
  _Pragma("unroll") \
  for (int j=0;j<4;j++){ \
    int r_ = wm + (IM)*16 + quad*4 + j; \
    float e0 = exp2f(fmaf(A0[j], c1, rs0)); \
    float e1 = exp2f(fmaf(A1[j], c1, rs1)); \
    float e2 = exp2f(fmaf(A2[j], c1, rs2)); \
    float e3 = exp2f(fmaf(A3[j], c1, rs3)); \
    A0[j]=e0; A1[j]=e1; A2[j]=e2; A3[j]=e3; \
    float s = (e0+e1)+(e2+e3); \
    s += __shfl_xor(s,1); s += __shfl_xor(s,2); \
    s += __shfl_xor(s,4); s += __shfl_xor(s,8); \
    if (l16==0) rbufB[(w&1)*128 + r_] = s; \
  } } while(0)
  EXPSUM(0, acc00,acc01,acc02,acc03);
  EXPSUM(1, acc10,acc11,acc12,acc13);
  EXPSUM(2, acc20,acc21,acc22,acc23);
  EXPSUM(3, acc30,acc31,acc32,acc33);
#undef EXPSUM
  __syncthreads();
  float csum0=0.f, csum1=0.f, csum2=0.f, csum3=0.f;
#define CSUM(IM,A0,A1,A2,A3) do { \
  _Pragma("unroll") \
  for (int j=0;j<4;j++){ \
    int r_ = wm + (IM)*16 + quad*4 + j; \
    float inv = __builtin_amdgcn_rcpf(rbufB[r_]+rbufB[128+r_]); \
    csum0 += A0[j]*inv; csum1 += A1[j]*inv; \
    csum2 += A2[j]*inv; csum3 += A3[j]*inv; \
  } } while(0)
  CSUM(0, acc00,acc01,acc02,acc03);
  CSUM(1, acc10,acc11,acc12,acc13);
  CSUM(2, acc20,acc21,acc22,acc23);
  CSUM(3, acc30,acc31,acc32,acc33);
#undef CSUM
  csum0 += __shfl_xor(csum0,16); csum0 += __shfl_xor(csum0,32);
  csum1 += __shfl_xor(csum1,16); csum1 += __shfl_xor(csum1,32);
  csum2 += __shfl_xor(csum2,16); csum2 += __shfl_xor(csum2,32);
  csum3 += __shfl_xor(csum3,16); csum3 += __shfl_xor(csum3,32);
  if (quad == 0){
    rbufA[(w>>1)*128 + wn      + l16] = csum0;
    rbufA[(w>>1)*128 + wn + 16 + l16] = csum1;
    rbufA[(w>>1)*128 + wn + 32 + l16] = csum2;
    rbufA[(w>>1)*128 + wn + 48 + l16] = csum3;
  }
  __syncthreads();
  if (tid < 128)
    ptbf[((size_t)b*128 + e)*128 + tid] =
        f2bf((rbufA[tid] + rbufA[128+tid]) * 0.0078125f); // /S
}

// ---------------- ctx2: ctx[b][e][h] = ptot_b[e][t] @ Vt_b[h][t]^T, K=128 ------------
__global__ __launch_bounds__(256, 1) void ctx2(
    const u16* __restrict__ ptbf, const u16* __restrict__ vtb,
    u16* __restrict__ ctxb)
{
  __shared__ __align__(16) u16 sA[128*64];
  __shared__ __align__(16) u16 sB[128*64];
  int b = blockIdx.y, nb = blockIdx.x;
  gemm128_core<128,128,false>(ptbf + (size_t)b*16384,
                              vtb + (size_t)b*98304 + (size_t)nb*16384,
                              nullptr, ctxb + (size_t)b*98304, 0, nb, sA, sB);
}

// ---------------- fin: LN(ctx) + dual matching scores, one block per (b,e) -----------
__global__ __launch_bounds__(256) void fin(
    const u16* __restrict__ ctxb, const u16* __restrict__ clsfc,
    const float* __restrict__ ecls, const float* __restrict__ mcls,
    const float* __restrict__ lng, const float* __restrict__ lnb,
    float* __restrict__ out)
{
  int bi = blockIdx.x;          // b*128 + e
  int b = bi >> 7, e = bi & 127;
  int tid = threadIdx.x;
  int lane = tid & 63, w = tid >> 6;
  __shared__ float redbuf[8];
  const u16* cr = ctxb + ((size_t)b*128 + e)*768;
  float a0 = bf2f(cr[tid]), a1 = bf2f(cr[tid+256]), a2 = bf2f(cr[tid+512]);
  float s1 = a0+a1+a2;
  float s2 = a0*a0 + a1*a1 + a2*a2;
  #pragma unroll
  for (int d2=1; d2<64; d2<<=1){ s1 += __shfl_xor(s1,d2); s2 += __shfl_xor(s2,d2); }
  if (lane==0){ redbuf[w]=s1; redbuf[4+w]=s2; }
  __syncthreads();
  s1 = redbuf[0]+redbuf[1]+redbuf[2]+redbuf[3];
  s2 = redbuf[4]+redbuf[5]+redbuf[6]+redbuf[7];
  float mu = s1 * (1.0f/768.0f);
  float var = s2 * (1.0f/768.0f) - mu*mu;
  float rstd = rsqrtf(var + 1e-5f);
  float dd = 0.f;
  {
    int h = tid;
    float y = (a0-mu)*rstd*lng[h] + lnb[h];
    dd += y * bf2f(clsfc[e*768+h]) + mcls[b*768+h]*ecls[e*768+h];
    h = tid + 256;
    y = (a1-mu)*rstd*lng[h] + lnb[h];
    dd += y * bf2f(clsfc[e*768+h]) + mcls[b*768+h]*ecls[e*768+h];
    h = tid + 512;
    y = (a2-mu)*rstd*lng[h] + lnb[h];
    dd += y * bf2f(clsfc[e*768+h]) + mcls[b*768+h]*ecls[e*768+h];
  }
  #pragma unroll
  for (int d2=1; d2<64; d2<<=1) dd += __shfl_xor(dd,d2);
  __syncthreads();
  if (lane==0) redbuf[w] = dd;
  __syncthreads();
  if (tid==0) out[bi] = 0.5f * (redbuf[0]+redbuf[1]+redbuf[2]+redbuf[3]);
}

extern "C" void kernel_launch(void* const* d_in, const int* in_sizes, int n_in,
                              void* d_out, int out_size, void* d_ws, size_t ws_size,
                              hipStream_t stream)
{
  (void)in_sizes; (void)n_in; (void)out_size; (void)ws_size;
  const float* ecls = (const float*)d_in[0];
  const float* etok = (const float*)d_in[1];
  const float* mcls = (const float*)d_in[2];
  const float* mtok = (const float*)d_in[3];
  const float* Wq   = (const float*)d_in[4];
  const float* bq   = (const float*)d_in[5];
  const float* Wk   = (const float*)d_in[6];
  const float* bk   = (const float*)d_in[7];
  const float* Wv   = (const float*)d_in[8];
  const float* bv   = (const float*)d_in[9];
  const float* Wc   = (const float*)d_in[10];
  const float* bc   = (const float*)d_in[11];
  const float* lng  = (const float*)d_in[12];
  const float* lnb  = (const float*)d_in[13];
  float* out = (float*)d_out;
  char* ws = (char*)d_ws;

  // workspace layout (bytes)
  u16* ent_bf  = (u16*)(ws + 0);          // 16384x768 bf16 = 25165824
  u16* men_bf  = (u16*)(ws + 25165824);   //  4096x768 bf16 =  6291456
  u16* ecls_bf = (u16*)(ws + 31457280);   //   128x768 bf16 =   196608
  u16* wvt     = (u16*)(ws + 31653888);   //   768x768 bf16 =  1179648 (transposed)
  u16* wct     = (u16*)(ws + 32833536);   //   768x768 bf16
  u16* mtb     = (u16*)(ws + 34013184);   //   768x768 bf16 (Mt = Wq.Wk^T)
  u16* vtb     = (u16*)(ws + 35192832);   //  32x768x128 bf16 = 6291456 (V^T per b)
  u16* clsb    = (u16*)(ws + 41484288);   //   128x768 bf16 =   196608
  u16* gtb     = (u16*)(ws + 41680896);   //  4096x768 bf16 =  6291456
  float* rbias = (float*)(ws + 47972352); //  4096 f32      =    16384
  float* wrb   = (float*)(ws + 47988736); //  769 f32 (wr + bkbq)
  float* c2b   = (float*)(ws + 47992832); //  768 f32
  u16* ptbf    = (u16*)(ws + 47996928);   //  32x128x128 bf16 = 1048576
  u16* ctxb    = (u16*)(ws + 49045504);   //  32x128x768 bf16 = 6291456

  prep<<<8929, 256, 0, stream>>>(etok, ent_bf, mtok, men_bf, ecls, ecls_bf,
                                 Wv, Wc, wvt, wct, Wq, Wk, mtb,
                                 bq, bk, wrb, c2b);
  proj<<<dim3(32,14), 256, 0, stream>>>(men_bf, ecls_bf, wvt, wct, mtb,
                                        bv, bc, c2b, wrb,
                                        vtb, gtb, clsb, rbias);
  attnk<<<4096, 256, 0, stream>>>(ent_bf, gtb, rbias, ptbf);
  ctx2<<<dim3(6,32), 256, 0, stream>>>(ptbf, vtb, ctxb);
  fin<<<4096, 256, 0, stream>>>(ctxb, clsb, ecls, mcls, lng, lnb, out);
}

// Round 10
// 247.051 us; speedup vs baseline: 1.5083x; 1.2107x over previous
//
#include <hip/hip_runtime.h>

typedef unsigned short u16;
typedef unsigned char u8;
typedef __bf16 bf16x8 __attribute__((ext_vector_type(8)));
typedef float f32x4 __attribute__((ext_vector_type(4)));
typedef u16 u16x8 __attribute__((ext_vector_type(8)));
typedef u16 u16x4 __attribute__((ext_vector_type(4)));
typedef int i32x8 __attribute__((ext_vector_type(8)));

static __device__ __forceinline__ u16 f2bf(float x){
  unsigned u = __float_as_uint(x);
  u += 0x7fffu + ((u >> 16) & 1u);
  return (u16)(u >> 16);
}
static __device__ __forceinline__ float bf2f(u16 u){
  return __uint_as_float(((unsigned)u) << 16);
}
static __device__ __forceinline__ u8 f2fp8(float x){
  int p = __builtin_amdgcn_cvt_pk_fp8_f32(x, x, 0, false);
  return (u8)(p & 0xff);
}

#define MFMA __builtin_amdgcn_mfma_f32_16x16x32_bf16
// fp8 e4m3 (cbsz=0, blgp=0), all block scales = 1.0 (e8m0 byte 0x7F)
#define MFMA8(A,B,C) __builtin_amdgcn_mfma_scale_f32_16x16x128_f8f6f4( \
    (A), (B), (C), 0, 0, 0, 0x7F7F7F7F, 0, 0x7F7F7F7F)

#define GLD1(GP, LP) __builtin_amdgcn_global_load_lds( \
    (const __attribute__((address_space(1))) unsigned int*)(GP), \
    (__attribute__((address_space(3))) unsigned int*)(LP), 16, 0, 0)

// ---- 16-acc core macros (named SSA vars only; arrays get memory-lowered) ----
#define DECL_ACC \
  f32x4 acc00={},acc01={},acc02={},acc03={}, \
        acc10={},acc11={},acc12={},acc13={}, \
        acc20={},acc21={},acc22={},acc23={}, \
        acc30={},acc31={},acc32={},acc33={};

#define CORE_SETUP \
  int tid = threadIdx.x; \
  int lane = tid & 63, w = tid >> 6; \
  int wm = (w >> 1) * 64, wn = (w & 1) * 64; \
  int quad = lane >> 4, l16 = lane & 15; \
  int r8 = lane >> 3, c8 = lane & 7; \
  int p0 = quad ^ (l16 & 7); \
  const u16* Agl = Ablk + (size_t)(w*32 + r8)*KS + (size_t)((c8 ^ r8)*8); \
  const u16* Bgl = Bblk + (size_t)(w*32 + r8)*KS + (size_t)((c8 ^ r8)*8); \
  u16* sAl = sA + w*2048; \
  u16* sBl = sB + w*2048; \
  const u16* paA0 = sA + (wm + l16)*64 + p0*8; \
  const u16* paA1 = sA + (wm + l16)*64 + (p0^4)*8; \
  const u16* paB0 = sB + (wn + l16)*64 + p0*8; \
  const u16* paB1 = sB + (wn + l16)*64 + (p0^4)*8;

#define GLDS8(K0) do { \
  const u16* ga_ = Agl + (K0); \
  const u16* gb_ = Bgl + (K0); \
  GLD1(ga_,         sAl);        GLD1(ga_ +  8*KS, sAl +  512); \
  GLD1(ga_ + 16*KS, sAl + 1024); GLD1(ga_ + 24*KS, sAl + 1536); \
  GLD1(gb_,         sBl);        GLD1(gb_ +  8*KS, sBl +  512); \
  GLD1(gb_ + 16*KS, sBl + 1024); GLD1(gb_ + 24*KS, sBl + 1536); \
} while(0)

#define KKSTEP(PA, PB) do { \
  bf16x8 a0 = *(const bf16x8*)(PA); \
  bf16x8 a1 = *(const bf16x8*)((PA) + 1024); \
  bf16x8 a2 = *(const bf16x8*)((PA) + 2048); \
  bf16x8 a3 = *(const bf16x8*)((PA) + 3072); \
  bf16x8 b0 = *(const bf16x8*)(PB); \
  bf16x8 b1 = *(const bf16x8*)((PB) + 1024); \
  bf16x8 b2 = *(const bf16x8*)((PB) + 2048); \
  bf16x8 b3 = *(const bf16x8*)((PB) + 3072); \
  acc00 = MFMA(a0,b0,acc00,0,0,0); acc01 = MFMA(a0,b1,acc01,0,0,0); \
  acc02 = MFMA(a0,b2,acc02,0,0,0); acc03 = MFMA(a0,b3,acc03,0,0,0); \
  acc10 = MFMA(a1,b0,acc10,0,0,0); acc11 = MFMA(a1,b1,acc11,0,0,0); \
  acc12 = MFMA(a1,b2,acc12,0,0,0); acc13 = MFMA(a1,b3,acc13,0,0,0); \
  acc20 = MFMA(a2,b0,acc20,0,0,0); acc21 = MFMA(a2,b1,acc21,0,0,0); \
  acc22 = MFMA(a2,b2,acc22,0,0,0); acc23 = MFMA(a2,b3,acc23,0,0,0); \
  acc30 = MFMA(a3,b0,acc30,0,0,0); acc31 = MFMA(a3,b1,acc31,0,0,0); \
  acc32 = MFMA(a3,b2,acc32,0,0,0); acc33 = MFMA(a3,b3,acc33,0,0,0); \
} while(0)

#define KLOOP do { \
  for (int k0 = 0; k0 < KLEN; k0 += 64){ \
    __syncthreads(); \
    GLDS8(k0); \
    __syncthreads(); \
    KKSTEP(paA0, paB0); \
    KKSTEP(paA1, paB1); \
  } } while(0)

// OM: 0 = u16 row-major(stride 768), 1 = u16 transposed(stride 128), 2 = fp8 row-major
template<int KLEN, int KS, int OM>
static __device__ __forceinline__ void gemm128_core(
    const u16* __restrict__ Ablk, const u16* __restrict__ Bblk,
    const float* __restrict__ bias, void* __restrict__ Cv,
    int mb, int nb, u16* sA, u16* sB)
{
  CORE_SETUP
  DECL_ACC
  KLOOP;
  int cb = nb*128 + wn + l16;
  float bb0=0.f, bb1=0.f, bb2=0.f, bb3=0.f;
  if (bias){ bb0=bias[cb]; bb1=bias[cb+16]; bb2=bias[cb+32]; bb3=bias[cb+48]; }
  if constexpr (OM == 0) {
    u16* C = (u16*)Cv;
#define GEPI(IM,A0,A1,A2,A3) do { \
  int r0_ = mb*128 + wm + (IM)*16 + quad*4; \
  _Pragma("unroll") \
  for (int j=0;j<4;j++){ \
    C[(size_t)(r0_+j)*768 + cb     ] = f2bf(A0[j]+bb0); \
    C[(size_t)(r0_+j)*768 + cb + 16] = f2bf(A1[j]+bb1); \
    C[(size_t)(r0_+j)*768 + cb + 32] = f2bf(A2[j]+bb2); \
    C[(size_t)(r0_+j)*768 + cb + 48] = f2bf(A3[j]+bb3); \
  } } while(0)
    GEPI(0, acc00,acc01,acc02,acc03);
    GEPI(1, acc10,acc11,acc12,acc13);
    GEPI(2, acc20,acc21,acc22,acc23);
    GEPI(3, acc30,acc31,acc32,acc33);
#undef GEPI
  } else if constexpr (OM == 1) {
    u16* C = (u16*)Cv;
#define GEPT(IM,A0,A1,A2,A3) do { \
  int t0_ = wm + (IM)*16 + quad*4; \
  u16x4 p0_ = {f2bf(A0[0]+bb0),f2bf(A0[1]+bb0),f2bf(A0[2]+bb0),f2bf(A0[3]+bb0)}; \
  u16x4 p1_ = {f2bf(A1[0]+bb1),f2bf(A1[1]+bb1),f2bf(A1[2]+bb1),f2bf(A1[3]+bb1)}; \
  u16x4 p2_ = {f2bf(A2[0]+bb2),f2bf(A2[1]+bb2),f2bf(A2[2]+bb2),f2bf(A2[3]+bb2)}; \
  u16x4 p3_ = {f2bf(A3[0]+bb3),f2bf(A3[1]+bb3),f2bf(A3[2]+bb3),f2bf(A3[3]+bb3)}; \
  *(u16x4*)(C + (size_t)(cb     )*128 + t0_) = p0_; \
  *(u16x4*)(C + (size_t)(cb + 16)*128 + t0_) = p1_; \
  *(u16x4*)(C + (size_t)(cb + 32)*128 + t0_) = p2_; \
  *(u16x4*)(C + (size_t)(cb + 48)*128 + t0_) = p3_; \
} while(0)
    GEPT(0, acc00,acc01,acc02,acc03);
    GEPT(1, acc10,acc11,acc12,acc13);
    GEPT(2, acc20,acc21,acc22,acc23);
    GEPT(3, acc30,acc31,acc32,acc33);
#undef GEPT
  } else {
    u8* C = (u8*)Cv;
#define GEP8(IM,A0,A1,A2,A3) do { \
  int r0_ = mb*128 + wm + (IM)*16 + quad*4; \
  _Pragma("unroll") \
  for (int j=0;j<4;j++){ \
    C[(size_t)(r0_+j)*768 + cb     ] = f2fp8(A0[j]+bb0); \
    C[(size_t)(r0_+j)*768 + cb + 16] = f2fp8(A1[j]+bb1); \
    C[(size_t)(r0_+j)*768 + cb + 32] = f2fp8(A2[j]+bb2); \
    C[(size_t)(r0_+j)*768 + cb + 48] = f2fp8(A3[j]+bb3); \
  } } while(0)
    GEP8(0, acc00,acc01,acc02,acc03);
    GEP8(1, acc10,acc11,acc12,acc13);
    GEP8(2, acc20,acc21,acc22,acc23);
    GEP8(3, acc30,acc31,acc32,acc33);
#undef GEP8
  }
}

// ------- prep: Mt = Wq.Wk^T (blocks 0..35 first) + wr/c2 (36..47) + bkbq (48)
// ------- + conversions (49..7776; etok -> FP8 e4m3) + 2 transposes (7777..8928)
__global__ __launch_bounds__(256) void prep(
    const float* __restrict__ etok, u8* __restrict__ ent8,
    const float* __restrict__ mtok, u16* __restrict__ menb,
    const float* __restrict__ ecls, u16* __restrict__ eclsb,
    const float* __restrict__ Wv, const float* __restrict__ Wc,
    u16* __restrict__ wvt, u16* __restrict__ wct,
    const float* __restrict__ Wq, const float* __restrict__ Wk,
    u16* __restrict__ mtb,
    const float* __restrict__ bq, const float* __restrict__ bk,
    float* __restrict__ wrb, float* __restrict__ c2b)
{
  __shared__ __align__(16) u16 shm[2*128*72];   // 36 KB, aliased per branch
  int blk = blockIdx.x;
  int tid = threadIdx.x;
  if (blk < 36){
    int mbq = blk/6, nbq = blk%6;
    u16* tA = shm; u16* tB = shm + 128*72;
    int lane = tid & 63, w = tid >> 6;
    int wm = (w >> 1) * 64, wn = (w & 1) * 64;
    int quad = lane >> 4, l16 = lane & 15;
    int sr = tid >> 3, sc = (tid & 7) * 8;
    const float* Ag = Wq + (size_t)(mbq*128+sr)*768 + sc;
    const float* Bg = Wk + (size_t)(nbq*128+sr)*768 + sc;
    u16* tAp = tA + sr*72 + sc;
    u16* tBp = tB + sr*72 + sc;
    DECL_ACC
    for (int k0=0;k0<768;k0+=64){
      __syncthreads();
#define STG(G) do { \
      float4 xa0=*(const float4*)(Ag+(G)*32*768+k0), xa1=*(const float4*)(Ag+(G)*32*768+k0+4); \
      float4 xb0=*(const float4*)(Bg+(G)*32*768+k0), xb1=*(const float4*)(Bg+(G)*32*768+k0+4); \
      u16x8 ra={f2bf(xa0.x),f2bf(xa0.y),f2bf(xa0.z),f2bf(xa0.w), \
                f2bf(xa1.x),f2bf(xa1.y),f2bf(xa1.z),f2bf(xa1.w)}; \
      u16x8 rb={f2bf(xb0.x),f2bf(xb0.y),f2bf(xb0.z),f2bf(xb0.w), \
                f2bf(xb1.x),f2bf(xb1.y),f2bf(xb1.z),f2bf(xb1.w)}; \
      *(u16x8*)(tAp+(G)*32*72)=ra; *(u16x8*)(tBp+(G)*32*72)=rb; \
      } while(0)
      STG(0); STG(1); STG(2); STG(3);
#undef STG
      __syncthreads();
#define KK72(KB) do { \
      const u16* pa_=tA+(wm+l16)*72+(KB)+quad*8; \
      const u16* pb_=tB+(wn+l16)*72+(KB)+quad*8; \
      bf16x8 a0=*(const bf16x8*)(pa_),      a1=*(const bf16x8*)(pa_+16*72); \
      bf16x8 a2=*(const bf16x8*)(pa_+32*72),a3=*(const bf16x8*)(pa_+48*72); \
      bf16x8 b0=*(const bf16x8*)(pb_),      b1=*(const bf16x8*)(pb_+16*72); \
      bf16x8 b2=*(const bf16x8*)(pb_+32*72),b3=*(const bf16x8*)(pb_+48*72); \
      acc00=MFMA(a0,b0,acc00,0,0,0); acc01=MFMA(a0,b1,acc01,0,0,0); \
      acc02=MFMA(a0,b2,acc02,0,0,0); acc03=MFMA(a0,b3,acc03,0,0,0); \
      acc10=MFMA(a1,b0,acc10,0,0,0); acc11=MFMA(a1,b1,acc11,0,0,0); \
      acc12=MFMA(a1,b2,acc12,0,0,0); acc13=MFMA(a1,b3,acc13,0,0,0); \
      acc20=MFMA(a2,b0,acc20,0,0,0); acc21=MFMA(a2,b1,acc21,0,0,0); \
      acc22=MFMA(a2,b2,acc22,0,0,0); acc23=MFMA(a2,b3,acc23,0,0,0); \
      acc30=MFMA(a3,b0,acc30,0,0,0); acc31=MFMA(a3,b1,acc31,0,0,0); \
      acc32=MFMA(a3,b2,acc32,0,0,0); acc33=MFMA(a3,b3,acc33,0,0,0); \
      } while(0)
      KK72(0); KK72(32);
#undef KK72
    }
    int cb = nbq*128 + wn + l16;
#define GEPM(IM,A0,A1,A2,A3) do { \
    int r0_ = mbq*128 + wm + (IM)*16 + quad*4; \
    _Pragma("unroll") \
    for (int j=0;j<4;j++){ \
      mtb[(size_t)(r0_+j)*768 + cb     ] = f2bf(A0[j]); \
      mtb[(size_t)(r0_+j)*768 + cb + 16] = f2bf(A1[j]); \
      mtb[(size_t)(r0_+j)*768 + cb + 32] = f2bf(A2[j]); \
      mtb[(size_t)(r0_+j)*768 + cb + 48] = f2bf(A3[j]); \
    } } while(0)
    GEPM(0, acc00,acc01,acc02,acc03);
    GEPM(1, acc10,acc11,acc12,acc13);
    GEPM(2, acc20,acc21,acc22,acc23);
    GEPM(3, acc30,acc31,acc32,acc33);
#undef GEPM
  } else if (blk < 48){
    int n = blk - 36;
    const float* M; const float* v; float* o;
    int j;
    if (n < 6){ M=Wk; v=bq; o=wrb; j=n; } else { M=Wq; v=bk; o=c2b; j=n-6; }
    int rr = tid >> 1, row = j*128 + rr;
    const float4* p = (const float4*)(M + (size_t)row*768 + (tid&1)*384);
    const float4* q = (const float4*)(v + (tid&1)*384);
    float s = 0.f;
    #pragma unroll 8
    for (int i=0;i<96;i++){
      float4 a=p[i], c=q[i];
      s += a.x*c.x + a.y*c.y + a.z*c.z + a.w*c.w;
    }
    s += __shfl_xor(s, 1);
    if (!(tid&1)) o[row] = s;
  } else if (blk == 48){
    float s = 0.f;
    for (int i=tid;i<768;i+=256) s += bk[i]*bq[i];
    #pragma unroll
    for (int d2=1; d2<64; d2<<=1) s += __shfl_xor(s,d2);
    float* red = (float*)shm;
    int lane = tid & 63, w = tid >> 6;
    if (lane==0) red[w]=s;
    __syncthreads();
    if (tid==0) wrb[768] = red[0]+red[1]+red[2]+red[3];
  } else if (blk < 7777){
    int i = (blk - 49) * 256 + tid;
    if (i < 1572864){
      // etok -> FP8 e4m3 (attnk A operand)
      const float4* s4 = (const float4*)etok;
      float4 a = s4[(size_t)i*2], b = s4[(size_t)i*2+1];
      int d0 = __builtin_amdgcn_cvt_pk_fp8_f32(a.x, a.y, 0, false);
      d0 = __builtin_amdgcn_cvt_pk_fp8_f32(a.z, a.w, d0, true);
      int d1 = __builtin_amdgcn_cvt_pk_fp8_f32(b.x, b.y, 0, false);
      d1 = __builtin_amdgcn_cvt_pk_fp8_f32(b.z, b.w, d1, true);
      int2 r; r.x = d0; r.y = d1;
      *(int2*)(ent8 + (size_t)i*8) = r;
    } else {
      const float* s; u16* d; int off;
      if (i < 1966080) { s=mtok; d=menb; off=i-1572864; }
      else             { s=ecls; d=eclsb; off=i-1966080; }
      const float4* s4 = (const float4*)s;
      float4 a = s4[(size_t)off*2], b = s4[(size_t)off*2+1];
      u16x8 r;
      r[0]=f2bf(a.x); r[1]=f2bf(a.y); r[2]=f2bf(a.z); r[3]=f2bf(a.w);
      r[4]=f2bf(b.x); r[5]=f2bf(b.y); r[6]=f2bf(b.z); r[7]=f2bf(b.w);
      *(u16x8*)(d + (size_t)off*8) = r;
    }
  } else {
    int n = blk - 7777;
    int z = n / 576, rem = n % 576;
    const float* s = z ? Wc : Wv;
    u16*         d = z ? wct : wvt;
    float* t = (float*)shm;       // [32][33]
    int bx = (rem % 24) * 32, by = (rem / 24) * 32;
    int tx = tid & 31, ty = (tid >> 5) * 4;
    for (int i=0;i<4;i++)
      t[(ty+i)*33 + tx] = s[(size_t)(by+ty+i)*768 + bx+tx];
    __syncthreads();
    for (int i=0;i<4;i++)
      d[(size_t)(bx+ty+i)*768 + by+tx] = f2bf(t[tx*33 + ty+i]);
  }
}

// ------- proj: V(->vtb transposed) y0..5 | G=men.Mt^T+c2 -> FP8 y6..11 | cls y12 |
// ------- rbias = men.wr + bkbq  y13 ------------------------------------------------
__global__ __launch_bounds__(256, 1) void proj(
    const u16* __restrict__ men, const u16* __restrict__ eclsb,
    const u16* __restrict__ wvt, const u16* __restrict__ wct,
    const u16* __restrict__ mtb,
    const float* __restrict__ bv, const float* __restrict__ bc,
    const float* __restrict__ c2b, const float* __restrict__ wrb,
    u16* __restrict__ vtb, u8* __restrict__ gt8, u16* __restrict__ clsb,
    float* __restrict__ rbias)
{
  __shared__ __align__(16) u16 sA[128*64];
  __shared__ __align__(16) u16 sB[128*64];
  int y = blockIdx.y, mb = blockIdx.x;
  if (y < 6){
    gemm128_core<768,768,1>(men + (size_t)mb*128*768, wvt + (size_t)y*128*768,
                            bv, vtb + (size_t)mb*98304, mb, y, sA, sB);
  } else if (y < 12){
    gemm128_core<768,768,2>(men + (size_t)mb*128*768, mtb + (size_t)(y-6)*128*768,
                            c2b, gt8, mb, y-6, sA, sB);
  } else if (y == 12){
    if (mb >= 6) return;
    gemm128_core<768,768,0>(eclsb, wct + (size_t)mb*128*768, bc, clsb, 0, mb, sA, sB);
  } else {
    int tid = threadIdx.x;
    int rr = tid >> 1, row = mb*128 + rr;
    const u16* p = men + (size_t)row*768 + (tid&1)*384;
    const float* q = wrb + (tid&1)*384;
    float s = 0.f;
    #pragma unroll 8
    for (int i=0;i<48;i++){
      u16x8 v = *(const u16x8*)(p + i*8);
      s += bf2f(v[0])*q[i*8]   + bf2f(v[1])*q[i*8+1]
         + bf2f(v[2])*q[i*8+2] + bf2f(v[3])*q[i*8+3]
         + bf2f(v[4])*q[i*8+4] + bf2f(v[5])*q[i*8+5]
         + bf2f(v[6])*q[i*8+6] + bf2f(v[7])*q[i*8+7];
    }
    s += __shfl_xor(s, 1);
    if (!(tid&1)) rbias[row] = s + wrb[768];
  }
}

// ------- attnk FP8: per (b,e) 128x128 scores via mfma_scale 16x16x128, K=768 -------
// LDS tile 128 rows x 128 B (fp8), 16B-block XOR swizzle c^(row&7); 6 K-chunks.
// No-max softmax over cols(t); column sums -> ptbf[b][e][t] bf16 /128.
__global__ __launch_bounds__(256, 1) void attnk(
    const u8* __restrict__ ent, const u8* __restrict__ gt,
    const float* __restrict__ rbias, u16* __restrict__ ptbf)
{
  __shared__ __align__(16) u8 sA[128*128];   // 16 KB
  __shared__ __align__(16) u8 sB[128*128];   // 16 KB
  __shared__ float rbufA[256];
  __shared__ float rbufB[256];
  int bi = blockIdx.x;          // b*128 + e (XCD=bi%8 -> disjoint ent sets)
  int b = bi >> 7, e = bi & 127;
  const u8* Ablk = ent + (size_t)e * 128 * 768;
  const u8* Bblk = gt  + (size_t)b * 128 * 768;
  int tid = threadIdx.x;
  int lane = tid & 63, w = tid >> 6;
  int wm = (w >> 1) * 64, wn = (w & 1) * 64;
  int quad = lane >> 4, l16 = lane & 15;
  int r8 = lane >> 3, c8 = lane & 7;
  const u8* Agl = Ablk + (size_t)(w*32 + r8)*768 + (size_t)((c8 ^ r8)*16);
  const u8* Bgl = Bblk + (size_t)(w*32 + r8)*768 + (size_t)((c8 ^ r8)*16);
  u8* sAl = sA + w*4096;
  u8* sBl = sB + w*4096;
  int rb = l16 & 7;
  const u8* paA0 = sA + (wm + l16)*128 + (((quad*2  )^rb)*16);
  const u8* paA1 = sA + (wm + l16)*128 + (((quad*2+1)^rb)*16);
  const u8* paB0 = sB + (wn + l16)*128 + (((quad*2  )^rb)*16);
  const u8* paB1 = sB + (wn + l16)*128 + (((quad*2+1)^rb)*16);
  DECL_ACC
#define LDI(V, P0, P1) i32x8 V; { \
  uint4 lo_ = *(const uint4*)(P0); uint4 hi_ = *(const uint4*)(P1); \
  V = (i32x8){(int)lo_.x,(int)lo_.y,(int)lo_.z,(int)lo_.w, \
              (int)hi_.x,(int)hi_.y,(int)hi_.z,(int)hi_.w}; }
  for (int k0 = 0; k0 < 768; k0 += 128){
    __syncthreads();
    {
      const u8* ga_ = Agl + k0;
      const u8* gb_ = Bgl + k0;
      GLD1(ga_,          sAl);        GLD1(ga_ +  8*768, sAl + 1024);
      GLD1(ga_ + 16*768, sAl + 2048); GLD1(ga_ + 24*768, sAl + 3072);
      GLD1(gb_,          sBl);        GLD1(gb_ +  8*768, sBl + 1024);
      GLD1(gb_ + 16*768, sBl + 2048); GLD1(gb_ + 24*768, sBl + 3072);
    }
    __syncthreads();
    LDI(b0, paB0,        paB1);
    LDI(b1, paB0 + 2048, paB1 + 2048);
    LDI(b2, paB0 + 4096, paB1 + 4096);
    LDI(b3, paB0 + 6144, paB1 + 6144);
    {
      LDI(a_, paA0, paA1);
      acc00=MFMA8(a_,b0,acc00); acc01=MFMA8(a_,b1,acc01);
      acc02=MFMA8(a_,b2,acc02); acc03=MFMA8(a_,b3,acc03);
    }
    {
      LDI(a_, paA0 + 2048, paA1 + 2048);
      acc10=MFMA8(a_,b0,acc10); acc11=MFMA8(a_,b1,acc11);
      acc12=MFMA8(a_,b2,acc12); acc13=MFMA8(a_,b3,acc13);
    }
    {
      LDI(a_, paA0 + 4096, paA1 + 4096);
      acc20=MFMA8(a_,b0,acc20); acc21=MFMA8(a_,b1,acc21);
      acc22=MFMA8(a_,b2,acc22); acc23=MFMA8(a_,b3,acc23);
    }
    {
      LDI(a_, paA0 + 6144, paA1 + 6144);
      acc30=MFMA8(a_,b0,acc30); acc31=MFMA8(a_,b1,acc31);
      acc32=MFMA8(a_,b2,acc32); acc33=MFMA8(a_,b3,acc33);
    }
  }
#undef LDI
  // exp arg = (dot + rbias)*scale*log2e = dot*c1 + rbias*c1
  const float c1 = 0.036084391824351615f * 1.4426950408889634f;
  float rs0 = rbias[b*128 + wn      + l16] * c1;
  float rs1 = rbias[b*128 + wn + 16 + l16] * c1;
  float rs2 = rbias[b*128 + wn + 32 + l16] * c1;
  float rs3 = rbias[b*128 + wn + 48 + l16] * c1;
  // rows: r = wm + im*16 + quad*4 + j ; cols: c = wn + in*16 + l16
#define EXPSUM(IM,A0,A1,A2,A3) do { \
  _Pragma("unroll") \
  for (int j=0;j<4;j++){ \
    int r_ = wm + (IM)*16 + quad*4 + j; \
    float e0 = exp2f(fmaf(A0[j], c1, rs0)); \
    float e1 = exp2f(fmaf(A1[j], c1, rs1)); \
    float e2 = exp2f(fmaf(A2[j], c1, rs2)); \
    float e3 = exp2f(fmaf(A3[j], c1, rs3)); \
    A0[j]=e0; A1[j]=e1; A2[j]=e2; A3[j]=e3; \
    float s = (e0+e1)+(e2+e3); \
    s += __shfl_xor(s,1); s += __shfl_xor(s,2); \
    s += __shfl_xor(s,4); s += __shfl_xor(s,8); \
    if (l16==0) rbufB[(w&1)*128 + r_] = s; \
  } } while(0)
  EXPSUM(0, acc00,acc01,acc02,acc03);
  EXPSUM(1, acc10,acc11,acc12,acc13);
  EXPSUM(2, acc20,acc21,acc22,acc23);
  EXPSUM(3, acc30,acc31,acc32,acc33);
#undef EXPSUM
  __syncthreads();
  float csum0=0.f, csum1=0.f, csum2=0.f, csum3=0.f;
#define CSUM(IM,A0,A1,A2,A3) do { \
  _Pragma("unroll") \
  for (int j=0;j<4;j++){ \
    int r_ = wm + (IM)*16 + quad*4 + j; \
    float inv = __builtin_amdgcn_rcpf(rbufB[r_]+rbufB[128+r_]); \
    csum0 += A0[j]*inv; csum1 += A1[j]*inv; \
    csum2 += A2[j]*inv; csum3 += A3[j]*inv; \
  } } while(0)
  CSUM(0, acc00,acc01,acc02,acc03);
  CSUM(1, acc10,acc11,acc12,acc13);
  CSUM(2, acc20,acc21,acc22,acc23);
  CSUM(3, acc30,acc31,acc32,acc33);
#undef CSUM
  csum0 += __shfl_xor(csum0,16); csum0 += __shfl_xor(csum0,32);
  csum1 += __shfl_xor(csum1,16); csum1 += __shfl_xor(csum1,32);
  csum2 += __shfl_xor(csum2,16); csum2 += __shfl_xor(csum2,32);
  csum3 += __shfl_xor(csum3,16); csum3 += __shfl_xor(csum3,32);
  if (quad == 0){
    rbufA[(w>>1)*128 + wn      + l16] = csum0;
    rbufA[(w>>1)*128 + wn + 16 + l16] = csum1;
    rbufA[(w>>1)*128 + wn + 32 + l16] = csum2;
    rbufA[(w>>1)*128 + wn + 48 + l16] = csum3;
  }
  __syncthreads();
  if (tid < 128)
    ptbf[((size_t)b*128 + e)*128 + tid] =
        f2bf((rbufA[tid] + rbufA[128+tid]) * 0.0078125f); // /S
}

// ---------------- ctx2: ctx[b][e][h] = ptot_b[e][t] @ Vt_b[h][t]^T, K=128 ------------
__global__ __launch_bounds__(256, 1) void ctx2(
    const u16* __restrict__ ptbf, const u16* __restrict__ vtb,
    u16* __restrict__ ctxb)
{
  __shared__ __align__(16) u16 sA[128*64];
  __shared__ __align__(16) u16 sB[128*64];
  int b = blockIdx.y, nb = blockIdx.x;
  gemm128_core<128,128,0>(ptbf + (size_t)b*16384,
                          vtb + (size_t)b*98304 + (size_t)nb*16384,
                          nullptr, ctxb + (size_t)b*98304, 0, nb, sA, sB);
}

// ---------------- fin: LN(ctx) + dual matching scores, one block per (b,e) -----------
__global__ __launch_bounds__(256) void fin(
    const u16* __restrict__ ctxb, const u16* __restrict__ clsfc,
    const float* __restrict__ ecls, const float* __restrict__ mcls,
    const float* __restrict__ lng, const float* __restrict__ lnb,
    float* __restrict__ out)
{
  int bi = blockIdx.x;          // b*128 + e
  int b = bi >> 7, e = bi & 127;
  int tid = threadIdx.x;
  int lane = tid & 63, w = tid >> 6;
  __shared__ float redbuf[8];
  const u16* cr = ctxb + ((size_t)b*128 + e)*768;
  float a0 = bf2f(cr[tid]), a1 = bf2f(cr[tid+256]), a2 = bf2f(cr[tid+512]);
  float s1 = a0+a1+a2;
  float s2 = a0*a0 + a1*a1 + a2*a2;
  #pragma unroll
  for (int d2=1; d2<64; d2<<=1){ s1 += __shfl_xor(s1,d2); s2 += __shfl_xor(s2,d2); }
  if (lane==0){ redbuf[w]=s1; redbuf[4+w]=s2; }
  __syncthreads();
  s1 = redbuf[0]+redbuf[1]+redbuf[2]+redbuf[3];
  s2 = redbuf[4]+redbuf[5]+redbuf[6]+redbuf[7];
  float mu = s1 * (1.0f/768.0f);
  float var = s2 * (1.0f/768.0f) - mu*mu;
  float rstd = rsqrtf(var + 1e-5f);
  float dd = 0.f;
  {
    int h = tid;
    float y = (a0-mu)*rstd*lng[h] + lnb[h];
    dd += y * bf2f(clsfc[e*768+h]) + mcls[b*768+h]*ecls[e*768+h];
    h = tid + 256;
    y = (a1-mu)*rstd*lng[h] + lnb[h];
    dd += y * bf2f(clsfc[e*768+h]) + mcls[b*768+h]*ecls[e*768+h];
    h = tid + 512;
    y = (a2-mu)*rstd*lng[h] + lnb[h];
    dd += y * bf2f(clsfc[e*768+h]) + mcls[b*768+h]*ecls[e*768+h];
  }
  #pragma unroll
  for (int d2=1; d2<64; d2<<=1) dd += __shfl_xor(dd,d2);
  __syncthreads();
  if (lane==0) redbuf[w] = dd;
  __syncthreads();
  if (tid==0) out[bi] = 0.5f * (redbuf[0]+redbuf[1]+redbuf[2]+redbuf[3]);
}

extern "C" void kernel_launch(void* const* d_in, const int* in_sizes, int n_in,
                              void* d_out, int out_size, void* d_ws, size_t ws_size,
                              hipStream_t stream)
{
  (void)in_sizes; (void)n_in; (void)out_size; (void)ws_size;
  const float* ecls = (const float*)d_in[0];
  const float* etok = (const float*)d_in[1];
  const float* mcls = (const float*)d_in[2];
  const float* mtok = (const float*)d_in[3];
  const float* Wq   = (const float*)d_in[4];
  const float* bq   = (const float*)d_in[5];
  const float* Wk   = (const float*)d_in[6];
  const float* bk   = (const float*)d_in[7];
  const float* Wv   = (const float*)d_in[8];
  const float* bv   = (const float*)d_in[9];
  const float* Wc   = (const float*)d_in[10];
  const float* bc   = (const float*)d_in[11];
  const float* lng  = (const float*)d_in[12];
  const float* lnb  = (const float*)d_in[13];
  float* out = (float*)d_out;
  char* ws = (char*)d_ws;

  // workspace layout (bytes)
  u8*  ent8    = (u8*)(ws + 0);           // 16384x768 fp8 = 12582912
  u16* men_bf  = (u16*)(ws + 12582912);   //  4096x768 bf16 = 6291456
  u16* ecls_bf = (u16*)(ws + 18874368);   //   128x768 bf16 =  196608
  u16* wvt     = (u16*)(ws + 19070976);   //   768x768 bf16 = 1179648 (transposed)
  u16* wct     = (u16*)(ws + 20250624);   //   768x768 bf16
  u16* mtb     = (u16*)(ws + 21430272);   //   768x768 bf16 (Mt = Wq.Wk^T)
  u16* vtb     = (u16*)(ws + 22609920);   //  32x768x128 bf16 = 6291456 (V^T per b)
  u16* clsb    = (u16*)(ws + 28901376);   //   128x768 bf16 =  196608
  u8*  gt8     = (u8*)(ws + 29097984);    //  4096x768 fp8 = 3145728
  float* rbias = (float*)(ws + 32243712); //  4096 f32 = 16384
  float* wrb   = (float*)(ws + 32260096); //  769 f32 (wr + bkbq)
  float* c2b   = (float*)(ws + 32264192); //  768 f32
  u16* ptbf    = (u16*)(ws + 32268288);   //  32x128x128 bf16 = 1048576
  u16* ctxb    = (u16*)(ws + 33316864);   //  32x128x768 bf16 = 6291456

  prep<<<8929, 256, 0, stream>>>(etok, ent8, mtok, men_bf, ecls, ecls_bf,
                                 Wv, Wc, wvt, wct, Wq, Wk, mtb,
                                 bq, bk, wrb, c2b);
  proj<<<dim3(32,14), 256, 0, stream>>>(men_bf, ecls_bf, wvt, wct, mtb,
                                        bv, bc, c2b, wrb,
                                        vtb, gt8, clsb, rbias);
  attnk<<<4096, 256, 0, stream>>>(ent8, gt8, rbias, ptbf);
  ctx2<<<dim3(6,32), 256, 0, stream>>>(ptbf, vtb, ctxb);
  fin<<<4096, 256, 0, stream>>>(ctxb, clsb, ecls, mcls, lng, lnb, out);
}